// Round 4
// baseline (43815.497 us; speedup 1.0000x reference)
//
#include <hip/hip_runtime.h>

// ---------------------------------------------------------------------------
// Sparse 3D U-Net, round 4: fused out-stationary sparse conv with
// register-blocked pairs (RM/thread), CIN-chunked staging, col-split (NCB).
//   inv[k][o] = input row for (offset k, out row o), -1 if absent.
//   Per k: compact valid pairs -> stage SB gathered rows (CC chans at a time)
//   -> each thread computes racc[RM][4] over CIN -> one LDS RMW per pair.
// No global atomics. Workspace ~181 MB.
// ---------------------------------------------------------------------------

#define CDIV(a, b) (((a) + (b)-1) / (b))

__global__ void fill_i32_k(int* __restrict__ buf, long n, int val) {
  long i = (long)blockIdx.x * blockDim.x + threadIdx.x;
  const long s = (long)gridDim.x * blockDim.x;
  for (; i < n; i += s) buf[i] = val;
}

// inv[k][om[k][p]] = im[k][p]  for valid pairs (om < n_out; pad == n_out).
__global__ void inv_build_k(const int* __restrict__ im, const int* __restrict__ om,
                            int P, const int* __restrict__ ndev, int nhost,
                            int* __restrict__ inv, int ldi) {
  const int n = (nhost >= 0) ? nhost : __ldg(ndev);
  const int k = blockIdx.y;
  const int p = blockIdx.x * 256 + threadIdx.x;
  if (p >= P) return;
  const int o = om[(long)k * P + p];
  if (o < n) inv[(long)k * ldi + o] = im[(long)k * P + p];
}

// Fused sparse conv: out[o, cb*COLS:+COLS] = sum_k fp[inv[k][o]] @ W[k][:, cols]
// Input row = concat(fpA[in][0:CIN1], fpB[in][0:CIN2]). CC = staging chunk.
template <int CIN1, int CIN2, int CC, int COUT, int NCB, int TP, int NPY, int RM>
__global__ __launch_bounds__(256) void sconv_fused_k(
    const float* __restrict__ fpA, const float* __restrict__ fpB,
    const float* __restrict__ W, const int* __restrict__ inv, int ldi,
    const int* __restrict__ ndev, int nhost, float* __restrict__ out) {
  constexpr int CIN = CIN1 + CIN2;
  constexpr int COLS = COUT / NCB;
  constexpr int NTX = COLS / 4;       // col-groups of 4
  constexpr int SB = NPY * RM;        // pairs per s-block
  constexpr int NCH = CIN / CC;       // staging chunks
  constexpr int CCV = CC / 4;
  constexpr int CP = CC + 4;          // staging pitch (bank step 4 per row)
  constexpr int OP = COLS + 4;        // acc pitch
  constexpr int CV = COLS / 4;
  constexpr int L1V = CIN1 / 4;
  static_assert(NTX * NPY == 256, "geometry");
  static_assert(SB <= TP, "sblock");
  static_assert(CIN % CC == 0 && CC % 4 == 0 && CIN1 % 4 == 0, "vec");

  const int n = (nhost >= 0) ? nhost : __ldg(ndev);
  const int o0 = blockIdx.x * TP;
  if (o0 >= n) return;
  const int rows = (n - o0 < TP) ? (n - o0) : TP;
  const int cb = blockIdx.y;

  __shared__ float acc[TP][OP];
  __shared__ float ast[SB][CP];
  __shared__ int lr[TP];
  __shared__ int li[TP];
  __shared__ int mcnt;

  for (int i = threadIdx.x; i < TP * CV; i += 256) {
    const int r = i / CV, c = (i - r * CV) << 2;
    *reinterpret_cast<float4*>(&acc[r][c]) = make_float4(0.f, 0.f, 0.f, 0.f);
  }

  const int tx = threadIdx.x % NTX;
  const int py = threadIdx.x / NTX;

  for (int k = 0; k < 27; ++k) {
    __syncthreads();
    if (threadIdx.x == 0) mcnt = 0;
    __syncthreads();
    if (threadIdx.x < rows) {
      const int iv = inv[(long)k * ldi + o0 + threadIdx.x];
      if (iv >= 0) {
        const int pos = atomicAdd(&mcnt, 1);
        lr[pos] = threadIdx.x;
        li[pos] = iv;
      }
    }
    __syncthreads();
    const int m = mcnt;
    if (m == 0) continue;
    const float* __restrict__ Wk = W + (long)k * (CIN * COUT) + cb * COLS + tx * 4;

    for (int s0 = 0; s0 < m; s0 += SB) {
      const int mb = (m - s0 < SB) ? (m - s0) : SB;
      float racc[RM][4];
#pragma unroll
      for (int mm = 0; mm < RM; ++mm) {
        racc[mm][0] = 0.f; racc[mm][1] = 0.f; racc[mm][2] = 0.f; racc[mm][3] = 0.f;
      }

#pragma unroll
      for (int ch = 0; ch < NCH; ++ch) {
        const int c0 = ch * CC;
        __syncthreads();  // ast free (prev compute / prev s-block done)
        for (int i = threadIdx.x; i < mb * CCV; i += 256) {
          const int s = i / CCV, q = i - s * CCV;
          const int g4 = (c0 >> 2) + q;
          const int in = li[s0 + s];
          float4 v;
          if (CIN2 == 0 || g4 < L1V)
            v = *reinterpret_cast<const float4*>(fpA + (long)in * CIN1 + (g4 << 2));
          else
            v = *reinterpret_cast<const float4*>(fpB + (long)in * CIN2 + ((g4 - L1V) << 2));
          *reinterpret_cast<float4*>(&ast[s][q << 2]) = v;
        }
        __syncthreads();

        for (int ci4 = 0; ci4 < CCV; ++ci4) {
          float4 a4[RM];
#pragma unroll
          for (int mm = 0; mm < RM; ++mm)
            a4[mm] = *reinterpret_cast<const float4*>(&ast[mm * NPY + py][ci4 << 2]);
          const float* __restrict__ wp = Wk + (long)(c0 + (ci4 << 2)) * COUT;
#pragma unroll
          for (int u = 0; u < 4; ++u) {
            const float4 w4 = *reinterpret_cast<const float4*>(wp + (long)u * COUT);
#pragma unroll
            for (int mm = 0; mm < RM; ++mm) {
              const float av = u == 0 ? a4[mm].x : u == 1 ? a4[mm].y : u == 2 ? a4[mm].z : a4[mm].w;
              racc[mm][0] = fmaf(av, w4.x, racc[mm][0]);
              racc[mm][1] = fmaf(av, w4.y, racc[mm][1]);
              racc[mm][2] = fmaf(av, w4.z, racc[mm][2]);
              racc[mm][3] = fmaf(av, w4.w, racc[mm][3]);
            }
          }
        }
      }
      // one LDS RMW per owned pair
#pragma unroll
      for (int mm = 0; mm < RM; ++mm) {
        const int sl = mm * NPY + py;
        if (sl < mb) {
          float* __restrict__ ap = &acc[lr[s0 + sl]][tx * 4];
          float4 c4 = *reinterpret_cast<const float4*>(ap);
          c4.x += racc[mm][0]; c4.y += racc[mm][1];
          c4.z += racc[mm][2]; c4.w += racc[mm][3];
          *reinterpret_cast<float4*>(ap) = c4;
        }
      }
    }
  }
  __syncthreads();
  for (int i = threadIdx.x; i < rows * CV; i += 256) {
    const int r = i / CV, c = (i - r * CV) << 2;
    *reinterpret_cast<float4*>(out + (long)(o0 + r) * COUT + cb * COLS + c) =
        *reinterpret_cast<const float4*>(&acc[r][c]);
  }
}

// ---- BN (two-pass) ----
template <int C>
__global__ __launch_bounds__(256) void bn_stats_k(
    const float* __restrict__ x, const int* __restrict__ ndev, int nhost,
    float* __restrict__ sums) {
  constexpr int RPB = 256 / C;
  const int n = (nhost >= 0) ? nhost : __ldg(ndev);
  const int c = threadIdx.x % C;
  const int rsub = threadIdx.x / C;
  float s = 0.f, ss = 0.f;
  const long step = (long)gridDim.x * RPB;
  for (long r = (long)blockIdx.x * RPB + rsub; r < n; r += step) {
    const float v = x[r * C + c];
    s += v;
    ss = fmaf(v, v, ss);
  }
  __shared__ float sh[2][256];
  sh[0][threadIdx.x] = s;
  sh[1][threadIdx.x] = ss;
  __syncthreads();
  if (rsub == 0) {
#pragma unroll
    for (int j = 1; j < RPB; ++j) {
      s += sh[0][c + j * C];
      ss += sh[1][c + j * C];
    }
    atomicAdd(&sums[c], s);
    atomicAdd(&sums[C + c], ss);
  }
}

__global__ void bn_finalize_k(const float* __restrict__ sums,
                              const float* __restrict__ g, const float* __restrict__ b,
                              const int* __restrict__ ndev, int nhost, int C,
                              float* __restrict__ sb) {
  const int c = threadIdx.x;
  if (c >= C) return;
  const float n = (float)((nhost >= 0) ? nhost : __ldg(ndev));
  const float mean = sums[c] / n;
  const float var = sums[C + c] / n - mean * mean;
  const float sc = g[c] * rsqrtf(var + 1e-5f);
  sb[c] = sc;
  sb[C + c] = fmaf(-mean, sc, b[c]);
}

__global__ void bn_apply_k(float* __restrict__ x, int cols, int lc,
                           const float* __restrict__ sb,
                           const int* __restrict__ ndev, int nhost) {
  const int n = (nhost >= 0) ? nhost : __ldg(ndev);
  const long total = (long)n * cols;
  const long stride = (long)gridDim.x * blockDim.x;
  for (long i = (long)blockIdx.x * blockDim.x + threadIdx.x; i < total; i += stride) {
    const long r = i >> lc;
    const int c = (int)(i & (cols - 1));
    const float v = x[r * cols + c];
    x[r * cols + c] = fmaxf(fmaf(v, sb[c], sb[cols + c]), 0.f);
  }
}

// out[N0,20] = concat(t2[N0,32], e1[N0,32]) @ Wf[64,20]
__global__ __launch_bounds__(256) void final_gemm_k(
    const float* __restrict__ t2, const float* __restrict__ e1,
    const float* __restrict__ Wf, float* __restrict__ out, int n0) {
  __shared__ float w[64 * 20];
  for (int i = threadIdx.x; i < 64 * 20; i += 256) w[i] = Wf[i];
  __syncthreads();
  const int r = blockIdx.x * 256 + threadIdx.x;
  if (r >= n0) return;
  float acc[20];
#pragma unroll
  for (int c = 0; c < 20; ++c) acc[c] = 0.f;
#pragma unroll
  for (int j = 0; j < 32; j += 4) {
    const float4 v = *reinterpret_cast<const float4*>(t2 + (long)r * 32 + j);
    const float vv[4] = {v.x, v.y, v.z, v.w};
#pragma unroll
    for (int u = 0; u < 4; ++u)
#pragma unroll
      for (int c = 0; c < 20; ++c) acc[c] = fmaf(vv[u], w[(j + u) * 20 + c], acc[c]);
  }
#pragma unroll
  for (int j = 0; j < 32; j += 4) {
    const float4 v = *reinterpret_cast<const float4*>(e1 + (long)r * 32 + j);
    const float vv[4] = {v.x, v.y, v.z, v.w};
#pragma unroll
    for (int u = 0; u < 4; ++u)
#pragma unroll
      for (int c = 0; c < 20; ++c) acc[c] = fmaf(vv[u], w[(32 + j + u) * 20 + c], acc[c]);
  }
  float* __restrict__ orow = out + (long)r * 20;
#pragma unroll
  for (int c = 0; c < 20; ++c) orow[c] = acc[c];
}

// ---------------------------------------------------------------------------

extern "C" void kernel_launch(void* const* d_in, const int* in_sizes, int n_in,
                              void* d_out, int out_size, void* d_ws, size_t ws_size,
                              hipStream_t stream) {
  const float* feats = (const float*)d_in[0];
  const float* W1 = (const float*)d_in[1];
  const float* W2 = (const float*)d_in[2];
  const float* W3 = (const float*)d_in[3];
  const float* W4 = (const float*)d_in[4];
  const float* D4w = (const float*)d_in[5];
  const float* D3w = (const float*)d_in[6];
  const float* D2w = (const float*)d_in[7];
  const float* Wf = (const float*)d_in[8];
  const float* g1 = (const float*)d_in[9];   const float* b1 = (const float*)d_in[10];
  const float* g2 = (const float*)d_in[11];  const float* b2 = (const float*)d_in[12];
  const float* g3 = (const float*)d_in[13];  const float* b3 = (const float*)d_in[14];
  const float* g4 = (const float*)d_in[15];  const float* b4 = (const float*)d_in[16];
  const float* gd4 = (const float*)d_in[17]; const float* bd4 = (const float*)d_in[18];
  const float* gd3 = (const float*)d_in[19]; const float* bd3 = (const float*)d_in[20];
  const float* gd2 = (const float*)d_in[21]; const float* bd2 = (const float*)d_in[22];
  const int* m1i = (const int*)d_in[23]; const int* m1o = (const int*)d_in[24];
  const int* m2i = (const int*)d_in[25]; const int* m2o = (const int*)d_in[26];
  const int* m3i = (const int*)d_in[27]; const int* m3o = (const int*)d_in[28];
  const int* m4i = (const int*)d_in[29]; const int* m4o = (const int*)d_in[30];
  const int* n1d = (const int*)d_in[31];
  const int* n2d = (const int*)d_in[32];
  const int* n3d = (const int*)d_in[33];

  const int N0 = in_sizes[0] / 4;
  const int P1 = in_sizes[23] / 27;
  const int P2 = in_sizes[25] / 27;
  const int P3 = in_sizes[27] / 27;
  const int P4 = in_sizes[29] / 27;
  const int MAXN2 = (N0 < 65536) ? N0 : 65536;  // 2 * 32^3
  const int MAXN3 = (N0 < 8192) ? N0 : 8192;    // 2 * 16^3

  float* ws = (float*)d_ws;
  size_t off = 0;
  auto alloc = [&](size_t nf) {
    float* p = ws + off;
    off += (nf + 63) & ~(size_t)63;
    return p;
  };
  float* e1 = alloc((size_t)N0 * 32);
  float* e2 = alloc((size_t)N0 * 64);      // n1 rows used
  float* e3 = alloc((size_t)MAXN2 * 128);
  float* e4 = alloc((size_t)MAXN3 * 256);
  float* t4 = alloc((size_t)MAXN2 * 128);
  float* t3 = alloc((size_t)N0 * 64);      // n1 rows used
  float* t2 = alloc((size_t)N0 * 32);
  float* stats = alloc(7 * 1024);
  int* inv = (int*)alloc((size_t)27 * N0);
  if (off * sizeof(float) > ws_size) return;  // loud fail if scratch too small

  hipMemsetAsync(stats, 0, 7 * 1024 * sizeof(float), stream);
  const dim3 blk(256);
#define ST(i) (stats + (i)*1024)
#define SB_(i) (stats + (i)*1024 + 512)

  // ---- conv1: 4->32, out rows N0 ----
  fill_i32_k<<<512, blk, 0, stream>>>(inv, (long)27 * N0, -1);
  inv_build_k<<<dim3(CDIV(P1, 256), 27), blk, 0, stream>>>(m1i, m1o, P1, nullptr, N0, inv, N0);
  sconv_fused_k<4, 0, 4, 32, 1, 256, 32, 2><<<CDIV(N0, 256), blk, 0, stream>>>(
      feats, nullptr, W1, inv, N0, nullptr, N0, e1);
  bn_stats_k<32><<<512, blk, 0, stream>>>(e1, nullptr, N0, ST(0));
  bn_finalize_k<<<1, blk, 0, stream>>>(ST(0), g1, b1, nullptr, N0, 32, SB_(0));
  bn_apply_k<<<1024, blk, 0, stream>>>(e1, 32, 5, SB_(0), nullptr, N0);

  // ---- conv2: 32->64, out rows n1 ----
  fill_i32_k<<<512, blk, 0, stream>>>(inv, (long)27 * N0, -1);
  inv_build_k<<<dim3(CDIV(P2, 256), 27), blk, 0, stream>>>(m2i, m2o, P2, n1d, -1, inv, N0);
  sconv_fused_k<32, 0, 32, 64, 1, 128, 16, 4><<<CDIV(N0, 128), blk, 0, stream>>>(
      e1, nullptr, W2, inv, N0, n1d, -1, e2);
  bn_stats_k<64><<<512, blk, 0, stream>>>(e2, n1d, -1, ST(1));
  bn_finalize_k<<<1, blk, 0, stream>>>(ST(1), g2, b2, n1d, -1, 64, SB_(1));
  bn_apply_k<<<1024, blk, 0, stream>>>(e2, 64, 6, SB_(1), n1d, -1);

  // ---- conv3: 64->128, out rows n2 ----
  fill_i32_k<<<512, blk, 0, stream>>>(inv, (long)27 * MAXN2, -1);
  inv_build_k<<<dim3(CDIV(P3, 256), 27), blk, 0, stream>>>(m3i, m3o, P3, n2d, -1, inv, MAXN2);
  sconv_fused_k<64, 0, 64, 128, 1, 64, 8, 8><<<CDIV(MAXN2, 64), blk, 0, stream>>>(
      e2, nullptr, W3, inv, MAXN2, n2d, -1, e3);
  bn_stats_k<128><<<512, blk, 0, stream>>>(e3, n2d, -1, ST(2));
  bn_finalize_k<<<1, blk, 0, stream>>>(ST(2), g3, b3, n2d, -1, 128, SB_(2));
  bn_apply_k<<<1024, blk, 0, stream>>>(e3, 128, 7, SB_(2), n2d, -1);

  // ---- conv4: 128->256, out rows n3, col-split x2 ----
  fill_i32_k<<<512, blk, 0, stream>>>(inv, (long)27 * MAXN3, -1);
  inv_build_k<<<dim3(CDIV(P4, 256), 27), blk, 0, stream>>>(m4i, m4o, P4, n3d, -1, inv, MAXN3);
  sconv_fused_k<128, 0, 128, 256, 2, 32, 8, 4><<<dim3(CDIV(MAXN3, 32), 2), blk, 0, stream>>>(
      e3, nullptr, W4, inv, MAXN3, n3d, -1, e4);
  bn_stats_k<256><<<512, blk, 0, stream>>>(e4, n3d, -1, ST(3));
  bn_finalize_k<<<1, blk, 0, stream>>>(ST(3), g4, b4, n3d, -1, 256, SB_(3));
  bn_apply_k<<<512, blk, 0, stream>>>(e4, 256, 8, SB_(3), n3d, -1);

  // ---- D4: tconv 256->128 (maps swapped), out rows n2 ----
  fill_i32_k<<<512, blk, 0, stream>>>(inv, (long)27 * MAXN2, -1);
  inv_build_k<<<dim3(CDIV(P4, 256), 27), blk, 0, stream>>>(m4o, m4i, P4, n2d, -1, inv, MAXN2);
  sconv_fused_k<256, 0, 128, 128, 1, 32, 8, 4><<<CDIV(MAXN2, 32), blk, 0, stream>>>(
      e4, nullptr, D4w, inv, MAXN2, n2d, -1, t4);
  bn_stats_k<128><<<512, blk, 0, stream>>>(t4, n2d, -1, ST(4));
  bn_finalize_k<<<1, blk, 0, stream>>>(ST(4), gd4, bd4, n2d, -1, 128, SB_(4));
  bn_apply_k<<<1024, blk, 0, stream>>>(t4, 128, 7, SB_(4), n2d, -1);

  // ---- D3: tconv concat(t4,e3)=256 -> 64, out rows n1 ----
  fill_i32_k<<<512, blk, 0, stream>>>(inv, (long)27 * N0, -1);
  inv_build_k<<<dim3(CDIV(P3, 256), 27), blk, 0, stream>>>(m3o, m3i, P3, n1d, -1, inv, N0);
  sconv_fused_k<128, 128, 128, 64, 1, 64, 16, 4><<<CDIV(N0, 64), blk, 0, stream>>>(
      t4, e3, D3w, inv, N0, n1d, -1, t3);
  bn_stats_k<64><<<512, blk, 0, stream>>>(t3, n1d, -1, ST(5));
  bn_finalize_k<<<1, blk, 0, stream>>>(ST(5), gd3, bd3, n1d, -1, 64, SB_(5));
  bn_apply_k<<<1024, blk, 0, stream>>>(t3, 64, 6, SB_(5), n1d, -1);

  // ---- D2: tconv concat(t3,e2)=128 -> 32, out rows N0 ----
  fill_i32_k<<<512, blk, 0, stream>>>(inv, (long)27 * N0, -1);
  inv_build_k<<<dim3(CDIV(P2, 256), 27), blk, 0, stream>>>(m2o, m2i, P2, nullptr, N0, inv, N0);
  sconv_fused_k<64, 64, 64, 32, 1, 128, 32, 4><<<CDIV(N0, 128), blk, 0, stream>>>(
      t3, e2, D2w, inv, N0, nullptr, N0, t2);
  bn_stats_k<32><<<512, blk, 0, stream>>>(t2, nullptr, N0, ST(6));
  bn_finalize_k<<<1, blk, 0, stream>>>(ST(6), gd2, bd2, nullptr, N0, 32, SB_(6));
  bn_apply_k<<<1024, blk, 0, stream>>>(t2, 32, 5, SB_(6), nullptr, N0);

  // ---- final 1x1: out = concat(t2, e1) @ Wf ----
  final_gemm_k<<<CDIV(N0, 256), blk, 0, stream>>>(t2, e1, Wf, (float*)d_out, N0);

#undef ST
#undef SB_
}

// Round 5
// 1369.591 us; speedup vs baseline: 31.9917x; 31.9917x over previous
//
#include <hip/hip_runtime.h>

// ---------------------------------------------------------------------------
// Sparse 3D U-Net, round 5: bf16 MFMA dense-over-offsets sparse conv.
//   inv[k][o] = input row for (offset k, out row o), -1 if absent.
//   mconv_k: block owns WAVES*16 out rows; C-frags in registers across all
//   27 offsets; per k stage frag-ordered W[k] (bf16) to LDS, gather A-frags
//   (zero for invalid), mfma_f32_16x16x32_bf16. Epilogue: bf16 store + fused
//   BN stats. No atomics to outputs, no contrib buffer, no compaction.
// Workspace ~102 MB. conv1 scalar; BN apply + final GEMM read bf16.
// ---------------------------------------------------------------------------

#define CDIV(a, b) (((a) + (b)-1) / (b))

typedef __attribute__((ext_vector_type(8))) short bf16x8;
typedef __attribute__((ext_vector_type(4))) float f32x4;

__device__ __forceinline__ unsigned short f2bf(float f) {
  union { float f; unsigned int u; } x{f};
  const unsigned int r = x.u + 0x7fffu + ((x.u >> 16) & 1u);
  return (unsigned short)(r >> 16);
}
__device__ __forceinline__ float bf2f(unsigned short h) {
  union { unsigned int u; float f; } x{(unsigned int)h << 16};
  return x.f;
}

__global__ void fill_i32_k(int* __restrict__ buf, long n, int val) {
  long i = (long)blockIdx.x * blockDim.x + threadIdx.x;
  const long s = (long)gridDim.x * blockDim.x;
  for (; i < n; i += s) buf[i] = val;
}

// inv[k][om[k][p]] = im[k][p] for valid pairs (om < n_out; pad == n_out).
__global__ void inv_build_k(const int* __restrict__ im, const int* __restrict__ om,
                            int P, const int* __restrict__ ndev, int nhost,
                            int* __restrict__ inv, int ldi) {
  const int n = (nhost >= 0) ? nhost : __ldg(ndev);
  const int k = blockIdx.y;
  const int p = blockIdx.x * 256 + threadIdx.x;
  if (p >= P) return;
  const int o = om[(long)k * P + p];
  if (o < n) inv[(long)k * ldi + o] = im[(long)k * P + p];
}

// W[27][CIN][COUT] fp32 -> bf16 in MFMA B-frag order:
// chunk ((k*NKK+kk)*NCC+cc): lane l, elem j = W[k][kk*32+(l>>4)*8+j][cc*16+(l&15)]
template <int CIN, int COUT>
__global__ __launch_bounds__(256) void prep_w_k(const float* __restrict__ W,
                                                unsigned short* __restrict__ Wf) {
  constexpr int NKK = CIN / 32, NCC = COUT / 16;
  const int t = blockIdx.x * 256 + threadIdx.x;
  if (t >= 27 * NKK * NCC * 64) return;
  const int l = t & 63;
  const int chunk = t >> 6;
  const int cc = chunk % NCC;
  const int kk = (chunk / NCC) % NKK;
  const int k = chunk / (NCC * NKK);
  const float* __restrict__ src =
      W + ((size_t)k * CIN + kk * 32 + (l >> 4) * 8) * COUT + cc * 16 + (l & 15);
  unsigned short* __restrict__ dst = Wf + (size_t)chunk * 512 + l * 8;
#pragma unroll
  for (int j = 0; j < 8; ++j) dst[j] = f2bf(src[(size_t)j * COUT]);
}

// Dense-over-k MFMA sparse conv. Input row = concat(actA[iv][0:CIN1], actB[iv][0:CIN2]).
template <int CIN1, int CIN2, int COUT, int WAVES>
__global__ __launch_bounds__(WAVES * 64) void mconv_k(
    const unsigned short* __restrict__ actA, const unsigned short* __restrict__ actB,
    const unsigned short* __restrict__ Wf, const int* __restrict__ inv, int ldi,
    const int* __restrict__ ndev, int nhost,
    unsigned short* __restrict__ out, float* __restrict__ stats) {
  constexpr int CIN = CIN1 + CIN2;
  constexpr int NKK = CIN / 32;
  constexpr int NCC = COUT / 16;
  constexpr int ROWS = WAVES * 16;
  constexpr int NT = WAVES * 64;
  __shared__ unsigned short wl[CIN * COUT];

  const int n = (nhost >= 0) ? nhost : __ldg(ndev);
  const int o0 = blockIdx.x * ROWS;
  if (o0 >= n) return;

  const int tid = threadIdx.x;
  const int w = tid >> 6;
  const int l = tid & 63;
  const int lrow = l & 15;
  const int lgrp = l >> 4;
  const int myrow = o0 + w * 16 + lrow;

  f32x4 acc[NCC];
#pragma unroll
  for (int cc = 0; cc < NCC; ++cc) acc[cc] = (f32x4){0.f, 0.f, 0.f, 0.f};

  for (int k = 0; k < 27; ++k) {
    __syncthreads();  // prior k's ds_reads complete before overwrite
    // stage frag-ordered W[k] into LDS (linear 16B copies)
    {
      const uint4* __restrict__ src = reinterpret_cast<const uint4*>(Wf + (size_t)k * CIN * COUT);
      uint4* dst = reinterpret_cast<uint4*>(wl);
      for (int i = tid; i < CIN * COUT / 8; i += NT) dst[i] = src[i];
    }
    // A fragments (gather; zero when no pair)
    const int iv = (myrow < n) ? inv[(size_t)k * ldi + myrow] : -1;
    bf16x8 a[NKK];
#pragma unroll
    for (int kk = 0; kk < NKK; ++kk) {
      if (iv >= 0) {
        const int cbase = kk * 32 + lgrp * 8;
        if (CIN2 == 0 || cbase < CIN1)
          a[kk] = *reinterpret_cast<const bf16x8*>(actA + (size_t)iv * CIN1 + cbase);
        else
          a[kk] = *reinterpret_cast<const bf16x8*>(actB + (size_t)iv * CIN2 + (cbase - CIN1));
      } else {
        a[kk] = (bf16x8){0, 0, 0, 0, 0, 0, 0, 0};
      }
    }
    __syncthreads();  // W[k] staged
#pragma unroll
    for (int kk = 0; kk < NKK; ++kk) {
#pragma unroll
      for (int cc = 0; cc < NCC; ++cc) {
        const bf16x8 b =
            *reinterpret_cast<const bf16x8*>(wl + ((kk * NCC + cc) * 64 + l) * 8);
        acc[cc] = __builtin_amdgcn_mfma_f32_16x16x32_bf16(a[kk], b, acc[cc], 0, 0, 0);
      }
    }
  }

  // epilogue: bf16 store + fused BN sum/sumsq (C layout: col=l&15, row=(l>>4)*4+r)
#pragma unroll
  for (int cc = 0; cc < NCC; ++cc) {
    float s = 0.f, ss = 0.f;
#pragma unroll
    for (int r = 0; r < 4; ++r) {
      const int grow = o0 + w * 16 + lgrp * 4 + r;
      const float v = acc[cc][r];
      if (grow < n) {
        out[(size_t)grow * COUT + cc * 16 + lrow] = f2bf(v);
        s += v;
        ss = fmaf(v, v, ss);
      }
    }
    s += __shfl_xor(s, 16); s += __shfl_xor(s, 32);
    ss += __shfl_xor(ss, 16); ss += __shfl_xor(ss, 32);
    if (lgrp == 0) {
      atomicAdd(&stats[cc * 16 + lrow], s);
      atomicAdd(&stats[COUT + cc * 16 + lrow], ss);
    }
  }
}

// conv1: 4->32 direct gather (fp32 compute, bf16 out)
__global__ __launch_bounds__(256) void conv1_k(
    const float* __restrict__ feats, const float* __restrict__ W1,
    const int* __restrict__ inv, int ldi, int n0, unsigned short* __restrict__ e1) {
  __shared__ float w[27 * 4 * 32];
  __shared__ float fr[8][27][4];
  __shared__ int ivs[8][27];
  for (int i = threadIdx.x; i < 27 * 4 * 32; i += 256) w[i] = W1[i];
  const int r0 = blockIdx.x * 8;
  for (int i = threadIdx.x; i < 8 * 27; i += 256) {
    const int r = i / 27, k = i - r * 27;
    const int iv = (r0 + r < n0) ? inv[(size_t)k * ldi + r0 + r] : -1;
    ivs[r][k] = iv;
    float4 v = make_float4(0.f, 0.f, 0.f, 0.f);
    if (iv >= 0) v = *reinterpret_cast<const float4*>(feats + (size_t)iv * 4);
    *reinterpret_cast<float4*>(&fr[r][k][0]) = v;
  }
  __syncthreads();
  const int c = threadIdx.x & 31;
  const int r = threadIdx.x >> 5;
  if (r0 + r >= n0) return;
  float acc = 0.f;
  for (int k = 0; k < 27; ++k) {
    if (ivs[r][k] >= 0) {
      const float* __restrict__ wr = &w[(k * 4) * 32 + c];
      acc = fmaf(fr[r][k][0], wr[0], acc);
      acc = fmaf(fr[r][k][1], wr[32], acc);
      acc = fmaf(fr[r][k][2], wr[64], acc);
      acc = fmaf(fr[r][k][3], wr[96], acc);
    }
  }
  e1[(size_t)(r0 + r) * 32 + c] = f2bf(acc);
}

// BN stats over bf16 activation (used for conv1 only)
template <int C>
__global__ __launch_bounds__(256) void bn_stats_bf16_k(
    const unsigned short* __restrict__ x, const int* __restrict__ ndev, int nhost,
    float* __restrict__ sums) {
  constexpr int RPB = 256 / C;
  const int n = (nhost >= 0) ? nhost : __ldg(ndev);
  const int c = threadIdx.x % C;
  const int rsub = threadIdx.x / C;
  float s = 0.f, ss = 0.f;
  const long step = (long)gridDim.x * RPB;
  for (long r = (long)blockIdx.x * RPB + rsub; r < n; r += step) {
    const float v = bf2f(x[r * C + c]);
    s += v;
    ss = fmaf(v, v, ss);
  }
  __shared__ float sh[2][256];
  sh[0][threadIdx.x] = s;
  sh[1][threadIdx.x] = ss;
  __syncthreads();
  if (rsub == 0) {
#pragma unroll
    for (int j = 1; j < RPB; ++j) { s += sh[0][c + j * C]; ss += sh[1][c + j * C]; }
    atomicAdd(&sums[c], s);
    atomicAdd(&sums[C + c], ss);
  }
}

__global__ void bn_finalize_k(const float* __restrict__ sums,
                              const float* __restrict__ g, const float* __restrict__ b,
                              const int* __restrict__ ndev, int nhost, int C,
                              float* __restrict__ sb) {
  const int c = threadIdx.x;
  if (c >= C) return;
  const float n = (float)((nhost >= 0) ? nhost : __ldg(ndev));
  const float mean = sums[c] / n;
  const float var = sums[C + c] / n - mean * mean;
  const float sc = g[c] * rsqrtf(var + 1e-5f);
  sb[c] = sc;
  sb[C + c] = fmaf(-mean, sc, b[c]);
}

// in-place BN+ReLU on bf16, 8 channels/thread
__global__ void bn_apply_bf16_k(unsigned short* __restrict__ x, int c8,
                                const float* __restrict__ sb, int C,
                                const int* __restrict__ ndev, int nhost) {
  const int n = (nhost >= 0) ? nhost : __ldg(ndev);
  const long total = (long)n * c8;
  const long stride = (long)gridDim.x * blockDim.x;
  for (long i = (long)blockIdx.x * blockDim.x + threadIdx.x; i < total; i += stride) {
    const int c0 = (int)(i & (c8 - 1)) << 3;
    uint4 v = *reinterpret_cast<uint4*>(x + i * 8);
    unsigned int uu[4] = {v.x, v.y, v.z, v.w};
#pragma unroll
    for (int q = 0; q < 4; ++q) {
      const float v0 = bf2f((unsigned short)(uu[q] & 0xffffu));
      const float v1 = bf2f((unsigned short)(uu[q] >> 16));
      const int cA = c0 + 2 * q, cB = c0 + 2 * q + 1;
      const float r0 = fmaxf(fmaf(v0, sb[cA], sb[C + cA]), 0.f);
      const float r1 = fmaxf(fmaf(v1, sb[cB], sb[C + cB]), 0.f);
      uu[q] = (unsigned int)f2bf(r0) | ((unsigned int)f2bf(r1) << 16);
    }
    v.x = uu[0]; v.y = uu[1]; v.z = uu[2]; v.w = uu[3];
    *reinterpret_cast<uint4*>(x + i * 8) = v;
  }
}

// out[N0,20] = concat(t2[N0,32], e1[N0,32]) @ Wf[64,20], bf16 inputs
__global__ __launch_bounds__(256) void final_gemm_k(
    const unsigned short* __restrict__ t2, const unsigned short* __restrict__ e1,
    const float* __restrict__ Wf, float* __restrict__ out, int n0) {
  __shared__ float w[64 * 20];
  for (int i = threadIdx.x; i < 64 * 20; i += 256) w[i] = Wf[i];
  __syncthreads();
  const int r = blockIdx.x * 256 + threadIdx.x;
  if (r >= n0) return;
  float acc[20];
#pragma unroll
  for (int c = 0; c < 20; ++c) acc[c] = 0.f;
  const unsigned short* __restrict__ rowA = t2 + (size_t)r * 32;
  const unsigned short* __restrict__ rowB = e1 + (size_t)r * 32;
#pragma unroll
  for (int j = 0; j < 32; ++j) {
    const float av = bf2f(rowA[j]);
#pragma unroll
    for (int c = 0; c < 20; ++c) acc[c] = fmaf(av, w[j * 20 + c], acc[c]);
  }
#pragma unroll
  for (int j = 0; j < 32; ++j) {
    const float av = bf2f(rowB[j]);
#pragma unroll
    for (int c = 0; c < 20; ++c) acc[c] = fmaf(av, w[(32 + j) * 20 + c], acc[c]);
  }
  float* __restrict__ orow = out + (size_t)r * 20;
#pragma unroll
  for (int c = 0; c < 20; ++c) orow[c] = acc[c];
}

// ---------------------------------------------------------------------------

extern "C" void kernel_launch(void* const* d_in, const int* in_sizes, int n_in,
                              void* d_out, int out_size, void* d_ws, size_t ws_size,
                              hipStream_t stream) {
  const float* feats = (const float*)d_in[0];
  const float* W1 = (const float*)d_in[1];
  const float* W2 = (const float*)d_in[2];
  const float* W3 = (const float*)d_in[3];
  const float* W4 = (const float*)d_in[4];
  const float* D4w = (const float*)d_in[5];
  const float* D3w = (const float*)d_in[6];
  const float* D2w = (const float*)d_in[7];
  const float* Wf = (const float*)d_in[8];
  const float* g1 = (const float*)d_in[9];   const float* b1 = (const float*)d_in[10];
  const float* g2 = (const float*)d_in[11];  const float* b2 = (const float*)d_in[12];
  const float* g3 = (const float*)d_in[13];  const float* b3 = (const float*)d_in[14];
  const float* g4 = (const float*)d_in[15];  const float* b4 = (const float*)d_in[16];
  const float* gd4 = (const float*)d_in[17]; const float* bd4 = (const float*)d_in[18];
  const float* gd3 = (const float*)d_in[19]; const float* bd3 = (const float*)d_in[20];
  const float* gd2 = (const float*)d_in[21]; const float* bd2 = (const float*)d_in[22];
  const int* m1i = (const int*)d_in[23]; const int* m1o = (const int*)d_in[24];
  const int* m2i = (const int*)d_in[25]; const int* m2o = (const int*)d_in[26];
  const int* m3i = (const int*)d_in[27]; const int* m3o = (const int*)d_in[28];
  const int* m4i = (const int*)d_in[29]; const int* m4o = (const int*)d_in[30];
  const int* n1d = (const int*)d_in[31];
  const int* n2d = (const int*)d_in[32];
  const int* n3d = (const int*)d_in[33];

  const int N0 = in_sizes[0] / 4;
  const int P1 = in_sizes[23] / 27;
  const int P2 = in_sizes[25] / 27;
  const int P3 = in_sizes[27] / 27;
  const int P4 = in_sizes[29] / 27;
  const int MAXN2 = (N0 < 65536) ? N0 : 65536;  // 2 * 32^3
  const int MAXN3 = (N0 < 8192) ? N0 : 8192;    // 2 * 16^3

  char* wsb = (char*)d_ws;
  size_t off = 0;
  auto alloc = [&](size_t bytes) {
    char* p = wsb + off;
    off = (off + bytes + 255) & ~(size_t)255;
    return p;
  };
  float* stats = (float*)alloc(7 * 1024 * 4);
  int* inv = (int*)alloc((size_t)27 * N0 * 4);
  unsigned short* e1 = (unsigned short*)alloc((size_t)N0 * 32 * 2);
  unsigned short* e2 = (unsigned short*)alloc((size_t)N0 * 64 * 2);
  unsigned short* e3 = (unsigned short*)alloc((size_t)MAXN2 * 128 * 2);
  unsigned short* e4 = (unsigned short*)alloc((size_t)MAXN3 * 256 * 2);
  unsigned short* t4 = (unsigned short*)alloc((size_t)MAXN2 * 128 * 2);
  unsigned short* t3 = (unsigned short*)alloc((size_t)N0 * 64 * 2);
  unsigned short* t2 = (unsigned short*)alloc((size_t)N0 * 32 * 2);
  unsigned short* Wf2 = (unsigned short*)alloc((size_t)27 * 32 * 64 * 2);
  unsigned short* Wf3 = (unsigned short*)alloc((size_t)27 * 64 * 128 * 2);
  unsigned short* Wf4 = (unsigned short*)alloc((size_t)27 * 128 * 256 * 2);
  unsigned short* WfD4 = (unsigned short*)alloc((size_t)27 * 256 * 128 * 2);
  unsigned short* WfD3 = (unsigned short*)alloc((size_t)27 * 256 * 64 * 2);
  unsigned short* WfD2 = (unsigned short*)alloc((size_t)27 * 128 * 32 * 2);
  if (off > ws_size) return;  // loud fail if scratch too small

  hipMemsetAsync(stats, 0, 7 * 1024 * 4, stream);
  const dim3 blk(256);
#define ST(i) (stats + (i)*1024)
#define SB_(i) (stats + (i)*1024 + 512)

  // ---- one-time weight prep (frag-ordered bf16) ----
  prep_w_k<32, 64><<<CDIV(27 * 1 * 4 * 64, 256), blk, 0, stream>>>(W2, Wf2);
  prep_w_k<64, 128><<<CDIV(27 * 2 * 8 * 64, 256), blk, 0, stream>>>(W3, Wf3);
  prep_w_k<128, 256><<<CDIV(27 * 4 * 16 * 64, 256), blk, 0, stream>>>(W4, Wf4);
  prep_w_k<256, 128><<<CDIV(27 * 8 * 8 * 64, 256), blk, 0, stream>>>(D4w, WfD4);
  prep_w_k<256, 64><<<CDIV(27 * 8 * 4 * 64, 256), blk, 0, stream>>>(D3w, WfD3);
  prep_w_k<128, 32><<<CDIV(27 * 4 * 2 * 64, 256), blk, 0, stream>>>(D2w, WfD2);

  // ---- conv1: 4->32 scalar, out rows N0 ----
  fill_i32_k<<<512, blk, 0, stream>>>(inv, (long)27 * N0, -1);
  inv_build_k<<<dim3(CDIV(P1, 256), 27), blk, 0, stream>>>(m1i, m1o, P1, nullptr, N0, inv, N0);
  conv1_k<<<CDIV(N0, 8), blk, 0, stream>>>(feats, W1, inv, N0, N0, e1);
  bn_stats_bf16_k<32><<<512, blk, 0, stream>>>(e1, nullptr, N0, ST(0));
  bn_finalize_k<<<1, blk, 0, stream>>>(ST(0), g1, b1, nullptr, N0, 32, SB_(0));
  bn_apply_bf16_k<<<1024, blk, 0, stream>>>(e1, 4, SB_(0), 32, nullptr, N0);

  // ---- conv2: 32->64 MFMA, out rows n1 ----
  fill_i32_k<<<512, blk, 0, stream>>>(inv, (long)27 * N0, -1);
  inv_build_k<<<dim3(CDIV(P2, 256), 27), blk, 0, stream>>>(m2i, m2o, P2, n1d, -1, inv, N0);
  mconv_k<32, 0, 64, 8><<<CDIV(N0, 128), 512, 0, stream>>>(
      e1, nullptr, Wf2, inv, N0, n1d, -1, e2, ST(1));
  bn_finalize_k<<<1, blk, 0, stream>>>(ST(1), g2, b2, n1d, -1, 64, SB_(1));
  bn_apply_bf16_k<<<1024, blk, 0, stream>>>(e2, 8, SB_(1), 64, n1d, -1);

  // ---- conv3: 64->128 MFMA, out rows n2 ----
  fill_i32_k<<<512, blk, 0, stream>>>(inv, (long)27 * MAXN2, -1);
  inv_build_k<<<dim3(CDIV(P3, 256), 27), blk, 0, stream>>>(m3i, m3o, P3, n2d, -1, inv, MAXN2);
  mconv_k<64, 0, 128, 8><<<CDIV(MAXN2, 128), 512, 0, stream>>>(
      e2, nullptr, Wf3, inv, MAXN2, n2d, -1, e3, ST(2));
  bn_finalize_k<<<1, blk, 0, stream>>>(ST(2), g3, b3, n2d, -1, 128, SB_(2));
  bn_apply_bf16_k<<<1024, blk, 0, stream>>>(e3, 16, SB_(2), 128, n2d, -1);

  // ---- conv4: 128->256 MFMA, out rows n3 ----
  fill_i32_k<<<512, blk, 0, stream>>>(inv, (long)27 * MAXN3, -1);
  inv_build_k<<<dim3(CDIV(P4, 256), 27), blk, 0, stream>>>(m4i, m4o, P4, n3d, -1, inv, MAXN3);
  mconv_k<128, 0, 256, 4><<<CDIV(MAXN3, 64), 256, 0, stream>>>(
      e3, nullptr, Wf4, inv, MAXN3, n3d, -1, e4, ST(3));
  bn_finalize_k<<<1, blk, 0, stream>>>(ST(3), g4, b4, n3d, -1, 256, SB_(3));
  bn_apply_bf16_k<<<512, blk, 0, stream>>>(e4, 32, SB_(3), 256, n3d, -1);

  // ---- D4: tconv 256->128 (maps swapped), out rows n2 ----
  fill_i32_k<<<512, blk, 0, stream>>>(inv, (long)27 * MAXN2, -1);
  inv_build_k<<<dim3(CDIV(P4, 256), 27), blk, 0, stream>>>(m4o, m4i, P4, n2d, -1, inv, MAXN2);
  mconv_k<256, 0, 128, 8><<<CDIV(MAXN2, 128), 512, 0, stream>>>(
      e4, nullptr, WfD4, inv, MAXN2, n2d, -1, t4, ST(4));
  bn_finalize_k<<<1, blk, 0, stream>>>(ST(4), gd4, bd4, n2d, -1, 128, SB_(4));
  bn_apply_bf16_k<<<1024, blk, 0, stream>>>(t4, 16, SB_(4), 128, n2d, -1);

  // ---- D3: tconv concat(t4,e3)=256 -> 64, out rows n1 ----
  fill_i32_k<<<512, blk, 0, stream>>>(inv, (long)27 * N0, -1);
  inv_build_k<<<dim3(CDIV(P3, 256), 27), blk, 0, stream>>>(m3o, m3i, P3, n1d, -1, inv, N0);
  mconv_k<128, 128, 64, 8><<<CDIV(N0, 128), 512, 0, stream>>>(
      t4, e3, WfD3, inv, N0, n1d, -1, t3, ST(5));
  bn_finalize_k<<<1, blk, 0, stream>>>(ST(5), gd3, bd3, n1d, -1, 64, SB_(5));
  bn_apply_bf16_k<<<1024, blk, 0, stream>>>(t3, 8, SB_(5), 64, n1d, -1);

  // ---- D2: tconv concat(t3,e2)=128 -> 32, out rows N0 ----
  fill_i32_k<<<512, blk, 0, stream>>>(inv, (long)27 * N0, -1);
  inv_build_k<<<dim3(CDIV(P2, 256), 27), blk, 0, stream>>>(m2o, m2i, P2, nullptr, N0, inv, N0);
  mconv_k<64, 64, 32, 8><<<CDIV(N0, 128), 512, 0, stream>>>(
      t3, e2, WfD2, inv, N0, nullptr, N0, t2, ST(6));
  bn_finalize_k<<<1, blk, 0, stream>>>(ST(6), gd2, bd2, nullptr, N0, 32, SB_(6));
  bn_apply_bf16_k<<<1024, blk, 0, stream>>>(t2, 4, SB_(6), 32, nullptr, N0);

  // ---- final 1x1: out = concat(t2, e1) @ Wf ----
  final_gemm_k<<<CDIV(N0, 256), blk, 0, stream>>>(t2, e1, Wf, (float*)d_out, N0);

#undef ST
#undef SB_
}

// Round 6
// 1183.538 us; speedup vs baseline: 37.0208x; 1.1572x over previous
//
#include <hip/hip_runtime.h>

// ---------------------------------------------------------------------------
// Sparse 3D U-Net, round 6: bf16 MFMA sparse conv with 2-phase pipeline.
//   - W[k] frag-ordered bf16, staged to LDS via global_load_lds (16B),
//     DOUBLE-BUFFERED: stage(k+1) issued before compute(k); one
//     __syncthreads per k drains vmcnt (stage) + lgkmcnt.
//   - A-fragments register-double-buffered (prefetch k+1).
//   - Wave-level skip when all 16 rows invalid for offset k (ballot).
//   - Col-split (NCB) keeps W LDS buffer <= 32KB (conv4 NCB=4, D4 NCB=2).
// Epilogue: bf16 store + fused BN stats. Workspace ~102 MB.
// ---------------------------------------------------------------------------

#define CDIV(a, b) (((a) + (b)-1) / (b))

typedef __attribute__((ext_vector_type(8))) short bf16x8;
typedef __attribute__((ext_vector_type(4))) float f32x4;

__device__ __forceinline__ unsigned short f2bf(float f) {
  union { float f; unsigned int u; } x{f};
  const unsigned int r = x.u + 0x7fffu + ((x.u >> 16) & 1u);
  return (unsigned short)(r >> 16);
}
__device__ __forceinline__ float bf2f(unsigned short h) {
  union { unsigned int u; float f; } x{(unsigned int)h << 16};
  return x.f;
}

__global__ void fill_i32_k(int* __restrict__ buf, long n, int val) {
  long i = (long)blockIdx.x * blockDim.x + threadIdx.x;
  const long s = (long)gridDim.x * blockDim.x;
  for (; i < n; i += s) buf[i] = val;
}

// inv[k][om[k][p]] = im[k][p] for valid pairs (om < n_out; pad == n_out).
__global__ void inv_build_k(const int* __restrict__ im, const int* __restrict__ om,
                            int P, const int* __restrict__ ndev, int nhost,
                            int* __restrict__ inv, int ldi) {
  const int n = (nhost >= 0) ? nhost : __ldg(ndev);
  const int k = blockIdx.y;
  const int p = blockIdx.x * 256 + threadIdx.x;
  if (p >= P) return;
  const int o = om[(long)k * P + p];
  if (o < n) inv[(long)k * ldi + o] = im[(long)k * P + p];
}

// W[27][CIN][COUT] fp32 -> bf16 in MFMA B-frag order:
// chunk ((k*NKK+kk)*NCC+cc): lane l, elem j = W[k][kk*32+(l>>4)*8+j][cc*16+(l&15)]
template <int CIN, int COUT>
__global__ __launch_bounds__(256) void prep_w_k(const float* __restrict__ W,
                                                unsigned short* __restrict__ Wf) {
  constexpr int NKK = CIN / 32, NCC = COUT / 16;
  const int t = blockIdx.x * 256 + threadIdx.x;
  if (t >= 27 * NKK * NCC * 64) return;
  const int l = t & 63;
  const int chunk = t >> 6;
  const int cc = chunk % NCC;
  const int kk = (chunk / NCC) % NKK;
  const int k = chunk / (NCC * NKK);
  const float* __restrict__ src =
      W + ((size_t)k * CIN + kk * 32 + (l >> 4) * 8) * COUT + cc * 16 + (l & 15);
  unsigned short* __restrict__ dst = Wf + (size_t)chunk * 512 + l * 8;
#pragma unroll
  for (int j = 0; j < 8; ++j) dst[j] = f2bf(src[(size_t)j * COUT]);
}

// 2-phase pipelined dense-over-k MFMA sparse conv.
template <int CIN1, int CIN2, int COUT, int NCB, int WAVES>
__global__ __launch_bounds__(WAVES * 64) void mconv_k(
    const unsigned short* __restrict__ actA, const unsigned short* __restrict__ actB,
    const unsigned short* __restrict__ Wf, const int* __restrict__ inv, int ldi,
    const int* __restrict__ ndev, int nhost,
    unsigned short* __restrict__ out, float* __restrict__ stats) {
  constexpr int CIN = CIN1 + CIN2;
  constexpr int NKK = CIN / 32;    // K-dim fragments
  constexpr int NCC = COUT / 16;   // total col fragments
  constexpr int NCCb = NCC / NCB;  // col fragments this block
  constexpr int ROWS = WAVES * 16;
  constexpr int T = NKK * NCCb;    // 1KB chunks per W buffer
  __shared__ unsigned short wl[2 * T * 512];

  const int n = (nhost >= 0) ? nhost : __ldg(ndev);
  const int o0 = blockIdx.x * ROWS;
  if (o0 >= n) return;
  const int cb = (NCB > 1) ? (int)blockIdx.y : 0;

  const int tid = threadIdx.x;
  const int w = tid >> 6;
  const int l = tid & 63;
  const int lrow = l & 15;
  const int lgrp = l >> 4;
  const int myrow = o0 + w * 16 + lrow;

  f32x4 acc[NCCb];
#pragma unroll
  for (int cc = 0; cc < NCCb; ++cc) acc[cc] = (f32x4){0.f, 0.f, 0.f, 0.f};

#define STAGE(kv, buf)                                                              \
  do {                                                                              \
    for (int t = w; t < T; t += WAVES) {                                            \
      const int kk_ = t / NCCb, ccl_ = t - kk_ * NCCb;                              \
      const unsigned short* src_ =                                                  \
          Wf + (((size_t)(kv)*NKK + kk_) * NCC + cb * NCCb + ccl_) * 512 + l * 8;   \
      __builtin_amdgcn_global_load_lds(                                             \
          (const __attribute__((address_space(1))) unsigned int*)src_,              \
          (__attribute__((address_space(3))) unsigned int*)(wl + (buf) * (T * 512) + t * 512), \
          16, 0, 0);                                                                \
    }                                                                               \
  } while (0)

#define LOADA(kv, a, anyv)                                                          \
  do {                                                                              \
    const int iv_ = (myrow < n) ? inv[(size_t)(kv)*ldi + myrow] : -1;               \
    anyv = (__ballot(iv_ >= 0) != 0ull);                                            \
    if (anyv) {                                                                     \
      _Pragma("unroll") for (int kk_ = 0; kk_ < NKK; ++kk_) {                       \
        if (iv_ >= 0) {                                                             \
          const int cb_ = kk_ * 32 + lgrp * 8;                                      \
          a[kk_] = (CIN2 == 0 || cb_ < CIN1)                                        \
                       ? *reinterpret_cast<const bf16x8*>(actA + (size_t)iv_ * CIN1 + cb_) \
                       : *reinterpret_cast<const bf16x8*>(actB + (size_t)iv_ * CIN2 + (cb_ - CIN1)); \
        } else {                                                                    \
          a[kk_] = (bf16x8){0, 0, 0, 0, 0, 0, 0, 0};                                \
        }                                                                           \
      }                                                                             \
    }                                                                               \
  } while (0)

#define COMPUTE(buf, a, anyv)                                                       \
  do {                                                                              \
    if (anyv) {                                                                     \
      _Pragma("unroll") for (int kk_ = 0; kk_ < NKK; ++kk_)                         \
      _Pragma("unroll") for (int cc_ = 0; cc_ < NCCb; ++cc_) {                      \
        const bf16x8 b_ = *reinterpret_cast<const bf16x8*>(                         \
            wl + (buf) * (T * 512) + ((kk_ * NCCb + cc_) * 64 + l) * 8);            \
        acc[cc_] = __builtin_amdgcn_mfma_f32_16x16x32_bf16(a[kk_], b_, acc[cc_], 0, 0, 0); \
      }                                                                             \
    }                                                                               \
  } while (0)

  bf16x8 a0[NKK], a1[NKK];
  bool v0 = false, v1 = false;

  STAGE(0, 0);
  LOADA(0, a0, v0);
  __syncthreads();  // drain stage(0) + A(0)

  int k = 0;
  while (true) {
    // even slot: compute buf0/a0, prefetch k+1 -> buf1/a1
    if (k + 1 < 27) { STAGE(k + 1, 1); LOADA(k + 1, a1, v1); }
    COMPUTE(0, a0, v0);
    __syncthreads();
    if (++k == 27) break;
    if (k + 1 < 27) { STAGE(k + 1, 0); LOADA(k + 1, a0, v0); }
    COMPUTE(1, a1, v1);
    __syncthreads();
    if (++k == 27) break;
  }

#undef STAGE
#undef LOADA
#undef COMPUTE

  // epilogue: bf16 store + fused BN stats (C layout: col=l&15, row=(l>>4)*4+r)
#pragma unroll
  for (int cc = 0; cc < NCCb; ++cc) {
    const int gcol = (cb * NCCb + cc) * 16 + lrow;
    float s = 0.f, ss = 0.f;
#pragma unroll
    for (int r = 0; r < 4; ++r) {
      const int grow = o0 + w * 16 + lgrp * 4 + r;
      const float v = acc[cc][r];
      if (grow < n) {
        out[(size_t)grow * COUT + gcol] = f2bf(v);
        s += v;
        ss = fmaf(v, v, ss);
      }
    }
    s += __shfl_xor(s, 16); s += __shfl_xor(s, 32);
    ss += __shfl_xor(ss, 16); ss += __shfl_xor(ss, 32);
    if (lgrp == 0) {
      atomicAdd(&stats[gcol], s);
      atomicAdd(&stats[COUT + gcol], ss);
    }
  }
}

// conv1: 4->32 direct gather (fp32 compute, bf16 out)
__global__ __launch_bounds__(256) void conv1_k(
    const float* __restrict__ feats, const float* __restrict__ W1,
    const int* __restrict__ inv, int ldi, int n0, unsigned short* __restrict__ e1) {
  __shared__ float w[27 * 4 * 32];
  __shared__ float fr[8][27][4];
  __shared__ int ivs[8][27];
  for (int i = threadIdx.x; i < 27 * 4 * 32; i += 256) w[i] = W1[i];
  const int r0 = blockIdx.x * 8;
  for (int i = threadIdx.x; i < 8 * 27; i += 256) {
    const int r = i / 27, k = i - r * 27;
    const int iv = (r0 + r < n0) ? inv[(size_t)k * ldi + r0 + r] : -1;
    ivs[r][k] = iv;
    float4 v = make_float4(0.f, 0.f, 0.f, 0.f);
    if (iv >= 0) v = *reinterpret_cast<const float4*>(feats + (size_t)iv * 4);
    *reinterpret_cast<float4*>(&fr[r][k][0]) = v;
  }
  __syncthreads();
  const int c = threadIdx.x & 31;
  const int r = threadIdx.x >> 5;
  if (r0 + r >= n0) return;
  float acc = 0.f;
  for (int k = 0; k < 27; ++k) {
    if (ivs[r][k] >= 0) {
      const float* __restrict__ wr = &w[(k * 4) * 32 + c];
      acc = fmaf(fr[r][k][0], wr[0], acc);
      acc = fmaf(fr[r][k][1], wr[32], acc);
      acc = fmaf(fr[r][k][2], wr[64], acc);
      acc = fmaf(fr[r][k][3], wr[96], acc);
    }
  }
  e1[(size_t)(r0 + r) * 32 + c] = f2bf(acc);
}

// BN stats over bf16 activation (used for conv1 only)
template <int C>
__global__ __launch_bounds__(256) void bn_stats_bf16_k(
    const unsigned short* __restrict__ x, const int* __restrict__ ndev, int nhost,
    float* __restrict__ sums) {
  constexpr int RPB = 256 / C;
  const int n = (nhost >= 0) ? nhost : __ldg(ndev);
  const int c = threadIdx.x % C;
  const int rsub = threadIdx.x / C;
  float s = 0.f, ss = 0.f;
  const long step = (long)gridDim.x * RPB;
  for (long r = (long)blockIdx.x * RPB + rsub; r < n; r += step) {
    const float v = bf2f(x[r * C + c]);
    s += v;
    ss = fmaf(v, v, ss);
  }
  __shared__ float sh[2][256];
  sh[0][threadIdx.x] = s;
  sh[1][threadIdx.x] = ss;
  __syncthreads();
  if (rsub == 0) {
#pragma unroll
    for (int j = 1; j < RPB; ++j) { s += sh[0][c + j * C]; ss += sh[1][c + j * C]; }
    atomicAdd(&sums[c], s);
    atomicAdd(&sums[C + c], ss);
  }
}

__global__ void bn_finalize_k(const float* __restrict__ sums,
                              const float* __restrict__ g, const float* __restrict__ b,
                              const int* __restrict__ ndev, int nhost, int C,
                              float* __restrict__ sb) {
  const int c = threadIdx.x;
  if (c >= C) return;
  const float n = (float)((nhost >= 0) ? nhost : __ldg(ndev));
  const float mean = sums[c] / n;
  const float var = sums[C + c] / n - mean * mean;
  const float sc = g[c] * rsqrtf(var + 1e-5f);
  sb[c] = sc;
  sb[C + c] = fmaf(-mean, sc, b[c]);
}

// in-place BN+ReLU on bf16, 8 channels/thread
__global__ void bn_apply_bf16_k(unsigned short* __restrict__ x, int c8,
                                const float* __restrict__ sb, int C,
                                const int* __restrict__ ndev, int nhost) {
  const int n = (nhost >= 0) ? nhost : __ldg(ndev);
  const long total = (long)n * c8;
  const long stride = (long)gridDim.x * blockDim.x;
  for (long i = (long)blockIdx.x * blockDim.x + threadIdx.x; i < total; i += stride) {
    const int c0 = (int)(i & (c8 - 1)) << 3;
    uint4 v = *reinterpret_cast<uint4*>(x + i * 8);
    unsigned int uu[4] = {v.x, v.y, v.z, v.w};
#pragma unroll
    for (int q = 0; q < 4; ++q) {
      const float v0 = bf2f((unsigned short)(uu[q] & 0xffffu));
      const float v1 = bf2f((unsigned short)(uu[q] >> 16));
      const int cA = c0 + 2 * q, cB = c0 + 2 * q + 1;
      const float r0 = fmaxf(fmaf(v0, sb[cA], sb[C + cA]), 0.f);
      const float r1 = fmaxf(fmaf(v1, sb[cB], sb[C + cB]), 0.f);
      uu[q] = (unsigned int)f2bf(r0) | ((unsigned int)f2bf(r1) << 16);
    }
    v.x = uu[0]; v.y = uu[1]; v.z = uu[2]; v.w = uu[3];
    *reinterpret_cast<uint4*>(x + i * 8) = v;
  }
}

// out[N0,20] = concat(t2[N0,32], e1[N0,32]) @ Wf[64,20], bf16 inputs
__global__ __launch_bounds__(256) void final_gemm_k(
    const unsigned short* __restrict__ t2, const unsigned short* __restrict__ e1,
    const float* __restrict__ Wf, float* __restrict__ out, int n0) {
  __shared__ float w[64 * 20];
  for (int i = threadIdx.x; i < 64 * 20; i += 256) w[i] = Wf[i];
  __syncthreads();
  const int r = blockIdx.x * 256 + threadIdx.x;
  if (r >= n0) return;
  float acc[20];
#pragma unroll
  for (int c = 0; c < 20; ++c) acc[c] = 0.f;
  const unsigned short* __restrict__ rowA = t2 + (size_t)r * 32;
  const unsigned short* __restrict__ rowB = e1 + (size_t)r * 32;
#pragma unroll
  for (int j = 0; j < 32; ++j) {
    const float av = bf2f(rowA[j]);
#pragma unroll
    for (int c = 0; c < 20; ++c) acc[c] = fmaf(av, w[j * 20 + c], acc[c]);
  }
#pragma unroll
  for (int j = 0; j < 32; ++j) {
    const float av = bf2f(rowB[j]);
#pragma unroll
    for (int c = 0; c < 20; ++c) acc[c] = fmaf(av, w[(32 + j) * 20 + c], acc[c]);
  }
  float* __restrict__ orow = out + (size_t)r * 20;
#pragma unroll
  for (int c = 0; c < 20; ++c) orow[c] = acc[c];
}

// ---------------------------------------------------------------------------

extern "C" void kernel_launch(void* const* d_in, const int* in_sizes, int n_in,
                              void* d_out, int out_size, void* d_ws, size_t ws_size,
                              hipStream_t stream) {
  const float* feats = (const float*)d_in[0];
  const float* W1 = (const float*)d_in[1];
  const float* W2 = (const float*)d_in[2];
  const float* W3 = (const float*)d_in[3];
  const float* W4 = (const float*)d_in[4];
  const float* D4w = (const float*)d_in[5];
  const float* D3w = (const float*)d_in[6];
  const float* D2w = (const float*)d_in[7];
  const float* Wf = (const float*)d_in[8];
  const float* g1 = (const float*)d_in[9];   const float* b1 = (const float*)d_in[10];
  const float* g2 = (const float*)d_in[11];  const float* b2 = (const float*)d_in[12];
  const float* g3 = (const float*)d_in[13];  const float* b3 = (const float*)d_in[14];
  const float* g4 = (const float*)d_in[15];  const float* b4 = (const float*)d_in[16];
  const float* gd4 = (const float*)d_in[17]; const float* bd4 = (const float*)d_in[18];
  const float* gd3 = (const float*)d_in[19]; const float* bd3 = (const float*)d_in[20];
  const float* gd2 = (const float*)d_in[21]; const float* bd2 = (const float*)d_in[22];
  const int* m1i = (const int*)d_in[23]; const int* m1o = (const int*)d_in[24];
  const int* m2i = (const int*)d_in[25]; const int* m2o = (const int*)d_in[26];
  const int* m3i = (const int*)d_in[27]; const int* m3o = (const int*)d_in[28];
  const int* m4i = (const int*)d_in[29]; const int* m4o = (const int*)d_in[30];
  const int* n1d = (const int*)d_in[31];
  const int* n2d = (const int*)d_in[32];
  const int* n3d = (const int*)d_in[33];

  const int N0 = in_sizes[0] / 4;
  const int P1 = in_sizes[23] / 27;
  const int P2 = in_sizes[25] / 27;
  const int P3 = in_sizes[27] / 27;
  const int P4 = in_sizes[29] / 27;
  const int MAXN2 = (N0 < 65536) ? N0 : 65536;  // 2 * 32^3
  const int MAXN3 = (N0 < 8192) ? N0 : 8192;    // 2 * 16^3

  char* wsb = (char*)d_ws;
  size_t off = 0;
  auto alloc = [&](size_t bytes) {
    char* p = wsb + off;
    off = (off + bytes + 255) & ~(size_t)255;
    return p;
  };
  float* stats = (float*)alloc(7 * 1024 * 4);
  int* inv = (int*)alloc((size_t)27 * N0 * 4);
  unsigned short* e1 = (unsigned short*)alloc((size_t)N0 * 32 * 2);
  unsigned short* e2 = (unsigned short*)alloc((size_t)N0 * 64 * 2);
  unsigned short* e3 = (unsigned short*)alloc((size_t)MAXN2 * 128 * 2);
  unsigned short* e4 = (unsigned short*)alloc((size_t)MAXN3 * 256 * 2);
  unsigned short* t4 = (unsigned short*)alloc((size_t)MAXN2 * 128 * 2);
  unsigned short* t3 = (unsigned short*)alloc((size_t)N0 * 64 * 2);
  unsigned short* t2 = (unsigned short*)alloc((size_t)N0 * 32 * 2);
  unsigned short* Wf2 = (unsigned short*)alloc((size_t)27 * 32 * 64 * 2);
  unsigned short* Wf3 = (unsigned short*)alloc((size_t)27 * 64 * 128 * 2);
  unsigned short* Wf4 = (unsigned short*)alloc((size_t)27 * 128 * 256 * 2);
  unsigned short* WfD4 = (unsigned short*)alloc((size_t)27 * 256 * 128 * 2);
  unsigned short* WfD3 = (unsigned short*)alloc((size_t)27 * 256 * 64 * 2);
  unsigned short* WfD2 = (unsigned short*)alloc((size_t)27 * 128 * 32 * 2);
  if (off > ws_size) return;  // loud fail if scratch too small

  hipMemsetAsync(stats, 0, 7 * 1024 * 4, stream);
  const dim3 blk(256);
#define ST(i) (stats + (i)*1024)
#define SB_(i) (stats + (i)*1024 + 512)

  // ---- one-time weight prep (frag-ordered bf16) ----
  prep_w_k<32, 64><<<CDIV(27 * 1 * 4 * 64, 256), blk, 0, stream>>>(W2, Wf2);
  prep_w_k<64, 128><<<CDIV(27 * 2 * 8 * 64, 256), blk, 0, stream>>>(W3, Wf3);
  prep_w_k<128, 256><<<CDIV(27 * 4 * 16 * 64, 256), blk, 0, stream>>>(W4, Wf4);
  prep_w_k<256, 128><<<CDIV(27 * 8 * 8 * 64, 256), blk, 0, stream>>>(D4w, WfD4);
  prep_w_k<256, 64><<<CDIV(27 * 8 * 4 * 64, 256), blk, 0, stream>>>(D3w, WfD3);
  prep_w_k<128, 32><<<CDIV(27 * 4 * 2 * 64, 256), blk, 0, stream>>>(D2w, WfD2);

  // ---- conv1: 4->32 scalar, out rows N0 ----
  fill_i32_k<<<512, blk, 0, stream>>>(inv, (long)27 * N0, -1);
  inv_build_k<<<dim3(CDIV(P1, 256), 27), blk, 0, stream>>>(m1i, m1o, P1, nullptr, N0, inv, N0);
  conv1_k<<<CDIV(N0, 8), blk, 0, stream>>>(feats, W1, inv, N0, N0, e1);
  bn_stats_bf16_k<32><<<512, blk, 0, stream>>>(e1, nullptr, N0, ST(0));
  bn_finalize_k<<<1, blk, 0, stream>>>(ST(0), g1, b1, nullptr, N0, 32, SB_(0));
  bn_apply_bf16_k<<<1024, blk, 0, stream>>>(e1, 4, SB_(0), 32, nullptr, N0);

  // ---- conv2: 32->64 MFMA, out rows n1 ----
  fill_i32_k<<<512, blk, 0, stream>>>(inv, (long)27 * N0, -1);
  inv_build_k<<<dim3(CDIV(P2, 256), 27), blk, 0, stream>>>(m2i, m2o, P2, n1d, -1, inv, N0);
  mconv_k<32, 0, 64, 1, 8><<<CDIV(N0, 128), 512, 0, stream>>>(
      e1, nullptr, Wf2, inv, N0, n1d, -1, e2, ST(1));
  bn_finalize_k<<<1, blk, 0, stream>>>(ST(1), g2, b2, n1d, -1, 64, SB_(1));
  bn_apply_bf16_k<<<1024, blk, 0, stream>>>(e2, 8, SB_(1), 64, n1d, -1);

  // ---- conv3: 64->128 MFMA, out rows n2 ----
  fill_i32_k<<<512, blk, 0, stream>>>(inv, (long)27 * MAXN2, -1);
  inv_build_k<<<dim3(CDIV(P3, 256), 27), blk, 0, stream>>>(m3i, m3o, P3, n2d, -1, inv, MAXN2);
  mconv_k<64, 0, 128, 1, 8><<<CDIV(MAXN2, 128), 512, 0, stream>>>(
      e2, nullptr, Wf3, inv, MAXN2, n2d, -1, e3, ST(2));
  bn_finalize_k<<<1, blk, 0, stream>>>(ST(2), g3, b3, n2d, -1, 128, SB_(2));
  bn_apply_bf16_k<<<1024, blk, 0, stream>>>(e3, 16, SB_(2), 128, n2d, -1);

  // ---- conv4: 128->256 MFMA, out rows n3, col-split x4 ----
  fill_i32_k<<<512, blk, 0, stream>>>(inv, (long)27 * MAXN3, -1);
  inv_build_k<<<dim3(CDIV(P4, 256), 27), blk, 0, stream>>>(m4i, m4o, P4, n3d, -1, inv, MAXN3);
  mconv_k<128, 0, 256, 4, 8><<<dim3(CDIV(MAXN3, 128), 4), 512, 0, stream>>>(
      e3, nullptr, Wf4, inv, MAXN3, n3d, -1, e4, ST(3));
  bn_finalize_k<<<1, blk, 0, stream>>>(ST(3), g4, b4, n3d, -1, 256, SB_(3));
  bn_apply_bf16_k<<<512, blk, 0, stream>>>(e4, 32, SB_(3), 256, n3d, -1);

  // ---- D4: tconv 256->128 (maps swapped), out rows n2, col-split x2 ----
  fill_i32_k<<<512, blk, 0, stream>>>(inv, (long)27 * MAXN2, -1);
  inv_build_k<<<dim3(CDIV(P4, 256), 27), blk, 0, stream>>>(m4o, m4i, P4, n2d, -1, inv, MAXN2);
  mconv_k<256, 0, 128, 2, 8><<<dim3(CDIV(MAXN2, 128), 2), 512, 0, stream>>>(
      e4, nullptr, WfD4, inv, MAXN2, n2d, -1, t4, ST(4));
  bn_finalize_k<<<1, blk, 0, stream>>>(ST(4), gd4, bd4, n2d, -1, 128, SB_(4));
  bn_apply_bf16_k<<<1024, blk, 0, stream>>>(t4, 16, SB_(4), 128, n2d, -1);

  // ---- D3: tconv concat(t4,e3)=256 -> 64, out rows n1 ----
  fill_i32_k<<<512, blk, 0, stream>>>(inv, (long)27 * N0, -1);
  inv_build_k<<<dim3(CDIV(P3, 256), 27), blk, 0, stream>>>(m3o, m3i, P3, n1d, -1, inv, N0);
  mconv_k<128, 128, 64, 1, 8><<<CDIV(N0, 128), 512, 0, stream>>>(
      t4, e3, WfD3, inv, N0, n1d, -1, t3, ST(5));
  bn_finalize_k<<<1, blk, 0, stream>>>(ST(5), gd3, bd3, n1d, -1, 64, SB_(5));
  bn_apply_bf16_k<<<1024, blk, 0, stream>>>(t3, 8, SB_(5), 64, n1d, -1);

  // ---- D2: tconv concat(t3,e2)=128 -> 32, out rows N0 ----
  fill_i32_k<<<512, blk, 0, stream>>>(inv, (long)27 * N0, -1);
  inv_build_k<<<dim3(CDIV(P2, 256), 27), blk, 0, stream>>>(m2o, m2i, P2, nullptr, N0, inv, N0);
  mconv_k<64, 64, 32, 1, 8><<<CDIV(N0, 128), 512, 0, stream>>>(
      t3, e2, WfD2, inv, N0, nullptr, N0, t2, ST(6));
  bn_finalize_k<<<1, blk, 0, stream>>>(ST(6), gd2, bd2, nullptr, N0, 32, SB_(6));
  bn_apply_bf16_k<<<1024, blk, 0, stream>>>(t2, 4, SB_(6), 32, nullptr, N0);

  // ---- final 1x1: out = concat(t2, e1) @ Wf ----
  final_gemm_k<<<CDIV(N0, 256), blk, 0, stream>>>(t2, e1, Wf, (float*)d_out, N0);

#undef ST
#undef SB_
}

// Round 7
// 627.229 us; speedup vs baseline: 69.8557x; 1.8869x over previous
//
#include <hip/hip_runtime.h>

// ---------------------------------------------------------------------------
// Sparse 3D U-Net, round 7: pair-compact bf16 MFMA for sparse layers,
// dense-over-k MFMA only for conv4 (84% fill).
//   Phase 1 (pgemm_k): per offset k, 16-pair tiles of VALID pairs; A gathered
//     via im; W[k] frag-ordered bf16 in LDS (global_load_lds, staged once per
//     block); ARM=2 row-frags share each B ds_read; compact bf16 contrib store.
//   Phase 2 (reduce_bf16_k): out[o] = sum_k contrib[inv[k][o]], atomic-free.
// Compute is proportional to actual pairs (~44 GF) instead of dense (~248 GF).
// Workspace ~196 MB (< 217 MB proven in round 1).
// ---------------------------------------------------------------------------

#define CDIV(a, b) (((a) + (b)-1) / (b))

typedef __attribute__((ext_vector_type(8))) short bf16x8;
typedef __attribute__((ext_vector_type(4))) float f32x4;

__device__ __forceinline__ unsigned short f2bf(float f) {
  union { float f; unsigned int u; } x{f};
  const unsigned int r = x.u + 0x7fffu + ((x.u >> 16) & 1u);
  return (unsigned short)(r >> 16);
}
__device__ __forceinline__ float bf2f(unsigned short h) {
  union { unsigned int u; float f; } x{(unsigned int)h << 16};
  return x.f;
}

__global__ void fill_i32_k(int* __restrict__ buf, long n, int val) {
  long i = (long)blockIdx.x * blockDim.x + threadIdx.x;
  const long s = (long)gridDim.x * blockDim.x;
  for (; i < n; i += s) buf[i] = val;
}

// per-offset valid counts via binary search (om rows = valid prefix + pad==n)
__global__ void kmap_bases_k(const int* __restrict__ om, int P,
                             const int* __restrict__ ndev, int nhost,
                             int* __restrict__ base) {
  __shared__ int cnt[27];
  const int n = (nhost >= 0) ? nhost : __ldg(ndev);
  const int k = threadIdx.x;
  if (k < 27) {
    const int* __restrict__ row = om + (long)k * P;
    int lo = 0, hi = P;
    while (lo < hi) {
      const int mid = (lo + hi) >> 1;
      if (row[mid] < n) lo = mid + 1; else hi = mid;
    }
    cnt[k] = lo;
  }
  __syncthreads();
  if (threadIdx.x == 0) {
    int acc = 0;
    for (int j = 0; j < 27; ++j) { base[j] = acc; acc += cnt[j]; }
    base[27] = acc;
  }
}

// inv[k][om[k][p]] = base[k] + p  (unique targets within k)
__global__ void inv_scatter_k(const int* __restrict__ om, int P,
                              const int* __restrict__ base,
                              int* __restrict__ inv, int ldi) {
  const int k = blockIdx.y;
  const int b0 = base[k];
  const int cnt = base[k + 1] - b0;
  const int p0 = blockIdx.x * 256;
  if (p0 >= cnt) return;
  const int p = p0 + threadIdx.x;
  if (p < cnt) inv[(long)k * ldi + om[(long)k * P + p]] = b0 + p;
}

// inv[k][om[k][p]] = im[k][p] for valid pairs (dense path: conv1, conv4)
__global__ void inv_build_k(const int* __restrict__ im, const int* __restrict__ om,
                            int P, const int* __restrict__ ndev, int nhost,
                            int* __restrict__ inv, int ldi) {
  const int n = (nhost >= 0) ? nhost : __ldg(ndev);
  const int k = blockIdx.y;
  const int p = blockIdx.x * 256 + threadIdx.x;
  if (p >= P) return;
  const int o = om[(long)k * P + p];
  if (o < n) inv[(long)k * ldi + o] = im[(long)k * P + p];
}

// W[27][CIN][COUT] fp32 -> bf16 in MFMA B-frag order:
// chunk ((k*NKK+kk)*NCC+cc): lane l, elem j = W[k][kk*32+(l>>4)*8+j][cc*16+(l&15)]
template <int CIN, int COUT>
__global__ __launch_bounds__(256) void prep_w_k(const float* __restrict__ W,
                                                unsigned short* __restrict__ Wf) {
  constexpr int NKK = CIN / 32, NCC = COUT / 16;
  const int t = blockIdx.x * 256 + threadIdx.x;
  if (t >= 27 * NKK * NCC * 64) return;
  const int l = t & 63;
  const int chunk = t >> 6;
  const int cc = chunk % NCC;
  const int kk = (chunk / NCC) % NKK;
  const int k = chunk / (NCC * NKK);
  const float* __restrict__ src =
      W + ((size_t)k * CIN + kk * 32 + (l >> 4) * 8) * COUT + cc * 16 + (l & 15);
  unsigned short* __restrict__ dst = Wf + (size_t)chunk * 512 + l * 8;
#pragma unroll
  for (int j = 0; j < 8; ++j) dst[j] = f2bf(src[(size_t)j * COUT]);
}

// Phase 1: compact per-offset pair GEMM. contrib[base[k]+p] = fp[im[k][p]] @ W[k]
template <int CIN1, int CIN2, int COUT, int ARM>
__global__ __launch_bounds__(256) void pgemm_k(
    const unsigned short* __restrict__ actA, const unsigned short* __restrict__ actB,
    const unsigned short* __restrict__ Wf, const int* __restrict__ im, int P,
    const int* __restrict__ base, unsigned short* __restrict__ contrib) {
  constexpr int CIN = CIN1 + CIN2;
  constexpr int NKK = CIN / 32;
  constexpr int NCC = COUT / 16;
  constexpr int T = NKK * NCC;       // 1KB W chunks
  constexpr int SPAN = 4 * ARM * 16; // pairs per block
  __shared__ unsigned short wl[T * 512];

  const int k = blockIdx.y;
  const int b0 = base[k];
  const int cnt = base[k + 1] - b0;
  if ((int)blockIdx.x * SPAN >= cnt) return;  // uniform: no barrier yet

  const int w = threadIdx.x >> 6;
  const int l = threadIdx.x & 63;
  for (int t = w; t < T; t += 4) {
    const unsigned short* src = Wf + ((size_t)k * T + t) * 512 + l * 8;
    __builtin_amdgcn_global_load_lds(
        (const __attribute__((address_space(1))) unsigned int*)src,
        (__attribute__((address_space(3))) unsigned int*)(wl + t * 512), 16, 0, 0);
  }
  __syncthreads();  // drains vmcnt: W[k] staged

  const int lrow = l & 15, lgrp = l >> 4;
  const int t0 = blockIdx.x * SPAN + w * (ARM * 16);

  bf16x8 a[ARM][NKK];
#pragma unroll
  for (int rm = 0; rm < ARM; ++rm) {
    const int p = t0 + rm * 16 + lrow;
    const int iv = (p < cnt) ? im[(size_t)k * P + p] : -1;
#pragma unroll
    for (int kk = 0; kk < NKK; ++kk) {
      if (iv >= 0) {
        const int cb = kk * 32 + lgrp * 8;
        a[rm][kk] = (CIN2 == 0 || cb < CIN1)
            ? *reinterpret_cast<const bf16x8*>(actA + (size_t)iv * CIN1 + cb)
            : *reinterpret_cast<const bf16x8*>(actB + (size_t)iv * CIN2 + (cb - CIN1));
      } else {
        a[rm][kk] = (bf16x8){0, 0, 0, 0, 0, 0, 0, 0};
      }
    }
  }

  f32x4 acc[ARM][NCC];
#pragma unroll
  for (int rm = 0; rm < ARM; ++rm)
#pragma unroll
    for (int cc = 0; cc < NCC; ++cc) acc[rm][cc] = (f32x4){0.f, 0.f, 0.f, 0.f};

#pragma unroll
  for (int kk = 0; kk < NKK; ++kk)
#pragma unroll
    for (int cc = 0; cc < NCC; ++cc) {
      const bf16x8 b =
          *reinterpret_cast<const bf16x8*>(wl + ((kk * NCC + cc) * 64 + l) * 8);
#pragma unroll
      for (int rm = 0; rm < ARM; ++rm)
        acc[rm][cc] = __builtin_amdgcn_mfma_f32_16x16x32_bf16(a[rm][kk], b, acc[rm][cc], 0, 0, 0);
    }

#pragma unroll
  for (int rm = 0; rm < ARM; ++rm)
#pragma unroll
    for (int cc = 0; cc < NCC; ++cc)
#pragma unroll
      for (int r = 0; r < 4; ++r) {
        const int p = t0 + rm * 16 + lgrp * 4 + r;
        if (p < cnt)
          contrib[(size_t)(b0 + p) * COUT + cc * 16 + lrow] = f2bf(acc[rm][cc][r]);
      }
}

// Phase 2: out[o] = sum_k contrib[inv[k][o]]  (bf16x8 chunks, fp32 accum)
template <int COUT>
__global__ __launch_bounds__(256) void reduce_bf16_k(
    const unsigned short* __restrict__ contrib, const int* __restrict__ inv, int ldi,
    const int* __restrict__ ndev, int nhost, unsigned short* __restrict__ out) {
  constexpr int TPR = COUT / 8;
  constexpr int RPB = 256 / TPR;
  const int n = (nhost >= 0) ? nhost : __ldg(ndev);
  const int r0 = blockIdx.x * RPB;
  if (r0 >= n) return;
  __shared__ int iv[RPB][28];
  for (int i = threadIdx.x; i < RPB * 27; i += 256) {
    const int r = i / 27, k = i - r * 27;
    iv[r][k] = (r0 + r < n) ? inv[(size_t)k * ldi + r0 + r] : -1;
  }
  __syncthreads();
  const int r = threadIdx.x / TPR;
  const int c8 = (threadIdx.x % TPR) * 8;
  if (r0 + r >= n) return;
  float s[8] = {0.f, 0.f, 0.f, 0.f, 0.f, 0.f, 0.f, 0.f};
  for (int k = 0; k < 27; ++k) {
    const int p = iv[r][k];
    if (p >= 0) {
      const bf16x8 v = *reinterpret_cast<const bf16x8*>(contrib + (size_t)p * COUT + c8);
#pragma unroll
      for (int j = 0; j < 8; ++j) s[j] += bf2f((unsigned short)v[j]);
    }
  }
  bf16x8 o;
#pragma unroll
  for (int j = 0; j < 8; ++j) o[j] = (short)f2bf(s[j]);
  *reinterpret_cast<bf16x8*>(out + (size_t)(r0 + r) * COUT + c8) = o;
}

// Dense-over-k 2-phase pipelined MFMA conv (used for conv4 only, ~84% fill).
template <int CIN1, int CIN2, int COUT, int NCB, int WAVES>
__global__ __launch_bounds__(WAVES * 64) void mconv_k(
    const unsigned short* __restrict__ actA, const unsigned short* __restrict__ actB,
    const unsigned short* __restrict__ Wf, const int* __restrict__ inv, int ldi,
    const int* __restrict__ ndev, int nhost,
    unsigned short* __restrict__ out, float* __restrict__ stats) {
  constexpr int CIN = CIN1 + CIN2;
  constexpr int NKK = CIN / 32;
  constexpr int NCC = COUT / 16;
  constexpr int NCCb = NCC / NCB;
  constexpr int ROWS = WAVES * 16;
  constexpr int T = NKK * NCCb;
  __shared__ unsigned short wl[2 * T * 512];

  const int n = (nhost >= 0) ? nhost : __ldg(ndev);
  const int o0 = blockIdx.x * ROWS;
  if (o0 >= n) return;
  const int cb = (NCB > 1) ? (int)blockIdx.y : 0;

  const int tid = threadIdx.x;
  const int w = tid >> 6;
  const int l = tid & 63;
  const int lrow = l & 15;
  const int lgrp = l >> 4;
  const int myrow = o0 + w * 16 + lrow;

  f32x4 acc[NCCb];
#pragma unroll
  for (int cc = 0; cc < NCCb; ++cc) acc[cc] = (f32x4){0.f, 0.f, 0.f, 0.f};

#define STAGE(kv, buf)                                                              \
  do {                                                                              \
    for (int t = w; t < T; t += WAVES) {                                            \
      const int kk_ = t / NCCb, ccl_ = t - kk_ * NCCb;                              \
      const unsigned short* src_ =                                                  \
          Wf + (((size_t)(kv)*NKK + kk_) * NCC + cb * NCCb + ccl_) * 512 + l * 8;   \
      __builtin_amdgcn_global_load_lds(                                             \
          (const __attribute__((address_space(1))) unsigned int*)src_,              \
          (__attribute__((address_space(3))) unsigned int*)(wl + (buf) * (T * 512) + t * 512), \
          16, 0, 0);                                                                \
    }                                                                               \
  } while (0)

#define LOADA(kv, a, anyv)                                                          \
  do {                                                                              \
    const int iv_ = (myrow < n) ? inv[(size_t)(kv)*ldi + myrow] : -1;               \
    anyv = (__ballot(iv_ >= 0) != 0ull);                                            \
    if (anyv) {                                                                     \
      _Pragma("unroll") for (int kk_ = 0; kk_ < NKK; ++kk_) {                       \
        if (iv_ >= 0) {                                                             \
          const int cb_ = kk_ * 32 + lgrp * 8;                                      \
          a[kk_] = (CIN2 == 0 || cb_ < CIN1)                                        \
                       ? *reinterpret_cast<const bf16x8*>(actA + (size_t)iv_ * CIN1 + cb_) \
                       : *reinterpret_cast<const bf16x8*>(actB + (size_t)iv_ * CIN2 + (cb_ - CIN1)); \
        } else {                                                                    \
          a[kk_] = (bf16x8){0, 0, 0, 0, 0, 0, 0, 0};                                \
        }                                                                           \
      }                                                                             \
    }                                                                               \
  } while (0)

#define COMPUTE(buf, a, anyv)                                                       \
  do {                                                                              \
    if (anyv) {                                                                     \
      _Pragma("unroll") for (int kk_ = 0; kk_ < NKK; ++kk_)                         \
      _Pragma("unroll") for (int cc_ = 0; cc_ < NCCb; ++cc_) {                      \
        const bf16x8 b_ = *reinterpret_cast<const bf16x8*>(                         \
            wl + (buf) * (T * 512) + ((kk_ * NCCb + cc_) * 64 + l) * 8);            \
        acc[cc_] = __builtin_amdgcn_mfma_f32_16x16x32_bf16(a[kk_], b_, acc[cc_], 0, 0, 0); \
      }                                                                             \
    }                                                                               \
  } while (0)

  bf16x8 a0[NKK], a1[NKK];
  bool v0 = false, v1 = false;

  STAGE(0, 0);
  LOADA(0, a0, v0);
  __syncthreads();

  int k = 0;
  while (true) {
    if (k + 1 < 27) { STAGE(k + 1, 1); LOADA(k + 1, a1, v1); }
    COMPUTE(0, a0, v0);
    __syncthreads();
    if (++k == 27) break;
    if (k + 1 < 27) { STAGE(k + 1, 0); LOADA(k + 1, a0, v0); }
    COMPUTE(1, a1, v1);
    __syncthreads();
    if (++k == 27) break;
  }

#undef STAGE
#undef LOADA
#undef COMPUTE

#pragma unroll
  for (int cc = 0; cc < NCCb; ++cc) {
    const int gcol = (cb * NCCb + cc) * 16 + lrow;
    float s = 0.f, ss = 0.f;
#pragma unroll
    for (int r = 0; r < 4; ++r) {
      const int grow = o0 + w * 16 + lgrp * 4 + r;
      const float v = acc[cc][r];
      if (grow < n) {
        out[(size_t)grow * COUT + gcol] = f2bf(v);
        s += v;
        ss = fmaf(v, v, ss);
      }
    }
    s += __shfl_xor(s, 16); s += __shfl_xor(s, 32);
    ss += __shfl_xor(ss, 16); ss += __shfl_xor(ss, 32);
    if (lgrp == 0) {
      atomicAdd(&stats[gcol], s);
      atomicAdd(&stats[COUT + gcol], ss);
    }
  }
}

// conv1: 4->32 direct gather (fp32 compute, bf16 out)
__global__ __launch_bounds__(256) void conv1_k(
    const float* __restrict__ feats, const float* __restrict__ W1,
    const int* __restrict__ inv, int ldi, int n0, unsigned short* __restrict__ e1) {
  __shared__ float w[27 * 4 * 32];
  __shared__ float fr[8][27][4];
  __shared__ int ivs[8][27];
  for (int i = threadIdx.x; i < 27 * 4 * 32; i += 256) w[i] = W1[i];
  const int r0 = blockIdx.x * 8;
  for (int i = threadIdx.x; i < 8 * 27; i += 256) {
    const int r = i / 27, k = i - r * 27;
    const int iv = (r0 + r < n0) ? inv[(size_t)k * ldi + r0 + r] : -1;
    ivs[r][k] = iv;
    float4 v = make_float4(0.f, 0.f, 0.f, 0.f);
    if (iv >= 0) v = *reinterpret_cast<const float4*>(feats + (size_t)iv * 4);
    *reinterpret_cast<float4*>(&fr[r][k][0]) = v;
  }
  __syncthreads();
  const int c = threadIdx.x & 31;
  const int r = threadIdx.x >> 5;
  if (r0 + r >= n0) return;
  float acc = 0.f;
  for (int k = 0; k < 27; ++k) {
    if (ivs[r][k] >= 0) {
      const float* __restrict__ wr = &w[(k * 4) * 32 + c];
      acc = fmaf(fr[r][k][0], wr[0], acc);
      acc = fmaf(fr[r][k][1], wr[32], acc);
      acc = fmaf(fr[r][k][2], wr[64], acc);
      acc = fmaf(fr[r][k][3], wr[96], acc);
    }
  }
  e1[(size_t)(r0 + r) * 32 + c] = f2bf(acc);
}

// ---- BN ----
template <int C>
__global__ __launch_bounds__(256) void bn_stats_bf16_k(
    const unsigned short* __restrict__ x, const int* __restrict__ ndev, int nhost,
    float* __restrict__ sums) {
  constexpr int RPB = 256 / C;
  const int n = (nhost >= 0) ? nhost : __ldg(ndev);
  const int c = threadIdx.x % C;
  const int rsub = threadIdx.x / C;
  float s = 0.f, ss = 0.f;
  const long step = (long)gridDim.x * RPB;
  for (long r = (long)blockIdx.x * RPB + rsub; r < n; r += step) {
    const float v = bf2f(x[r * C + c]);
    s += v;
    ss = fmaf(v, v, ss);
  }
  __shared__ float sh[2][256];
  sh[0][threadIdx.x] = s;
  sh[1][threadIdx.x] = ss;
  __syncthreads();
  if (rsub == 0) {
#pragma unroll
    for (int j = 1; j < RPB; ++j) { s += sh[0][c + j * C]; ss += sh[1][c + j * C]; }
    atomicAdd(&sums[c], s);
    atomicAdd(&sums[C + c], ss);
  }
}

__global__ void bn_finalize_k(const float* __restrict__ sums,
                              const float* __restrict__ g, const float* __restrict__ b,
                              const int* __restrict__ ndev, int nhost, int C,
                              float* __restrict__ sb) {
  const int c = threadIdx.x;
  if (c >= C) return;
  const float n = (float)((nhost >= 0) ? nhost : __ldg(ndev));
  const float mean = sums[c] / n;
  const float var = sums[C + c] / n - mean * mean;
  const float sc = g[c] * rsqrtf(var + 1e-5f);
  sb[c] = sc;
  sb[C + c] = fmaf(-mean, sc, b[c]);
}

__global__ void bn_apply_bf16_k(unsigned short* __restrict__ x, int c8,
                                const float* __restrict__ sb, int C,
                                const int* __restrict__ ndev, int nhost) {
  const int n = (nhost >= 0) ? nhost : __ldg(ndev);
  const long total = (long)n * c8;
  const long stride = (long)gridDim.x * blockDim.x;
  for (long i = (long)blockIdx.x * blockDim.x + threadIdx.x; i < total; i += stride) {
    const int c0 = (int)(i & (c8 - 1)) << 3;
    uint4 v = *reinterpret_cast<uint4*>(x + i * 8);
    unsigned int uu[4] = {v.x, v.y, v.z, v.w};
#pragma unroll
    for (int q = 0; q < 4; ++q) {
      const float v0 = bf2f((unsigned short)(uu[q] & 0xffffu));
      const float v1 = bf2f((unsigned short)(uu[q] >> 16));
      const int cA = c0 + 2 * q, cB = c0 + 2 * q + 1;
      const float r0 = fmaxf(fmaf(v0, sb[cA], sb[C + cA]), 0.f);
      const float r1 = fmaxf(fmaf(v1, sb[cB], sb[C + cB]), 0.f);
      uu[q] = (unsigned int)f2bf(r0) | ((unsigned int)f2bf(r1) << 16);
    }
    v.x = uu[0]; v.y = uu[1]; v.z = uu[2]; v.w = uu[3];
    *reinterpret_cast<uint4*>(x + i * 8) = v;
  }
}

// out[N0,20] = concat(t2[N0,32], e1[N0,32]) @ Wf[64,20], bf16 inputs
__global__ __launch_bounds__(256) void final_gemm_k(
    const unsigned short* __restrict__ t2, const unsigned short* __restrict__ e1,
    const float* __restrict__ Wf, float* __restrict__ out, int n0) {
  __shared__ float w[64 * 20];
  for (int i = threadIdx.x; i < 64 * 20; i += 256) w[i] = Wf[i];
  __syncthreads();
  const int r = blockIdx.x * 256 + threadIdx.x;
  if (r >= n0) return;
  float acc[20];
#pragma unroll
  for (int c = 0; c < 20; ++c) acc[c] = 0.f;
  const unsigned short* __restrict__ rowA = t2 + (size_t)r * 32;
  const unsigned short* __restrict__ rowB = e1 + (size_t)r * 32;
#pragma unroll
  for (int j = 0; j < 32; ++j) {
    const float av = bf2f(rowA[j]);
#pragma unroll
    for (int c = 0; c < 20; ++c) acc[c] = fmaf(av, w[j * 20 + c], acc[c]);
  }
#pragma unroll
  for (int j = 0; j < 32; ++j) {
    const float av = bf2f(rowB[j]);
#pragma unroll
    for (int c = 0; c < 20; ++c) acc[c] = fmaf(av, w[(32 + j) * 20 + c], acc[c]);
  }
  float* __restrict__ orow = out + (size_t)r * 20;
#pragma unroll
  for (int c = 0; c < 20; ++c) orow[c] = acc[c];
}

// ---------------------------------------------------------------------------

extern "C" void kernel_launch(void* const* d_in, const int* in_sizes, int n_in,
                              void* d_out, int out_size, void* d_ws, size_t ws_size,
                              hipStream_t stream) {
  const float* feats = (const float*)d_in[0];
  const float* W1 = (const float*)d_in[1];
  const float* W2 = (const float*)d_in[2];
  const float* W3 = (const float*)d_in[3];
  const float* W4 = (const float*)d_in[4];
  const float* D4w = (const float*)d_in[5];
  const float* D3w = (const float*)d_in[6];
  const float* D2w = (const float*)d_in[7];
  const float* Wf = (const float*)d_in[8];
  const float* g1 = (const float*)d_in[9];   const float* b1 = (const float*)d_in[10];
  const float* g2 = (const float*)d_in[11];  const float* b2 = (const float*)d_in[12];
  const float* g3 = (const float*)d_in[13];  const float* b3 = (const float*)d_in[14];
  const float* g4 = (const float*)d_in[15];  const float* b4 = (const float*)d_in[16];
  const float* gd4 = (const float*)d_in[17]; const float* bd4 = (const float*)d_in[18];
  const float* gd3 = (const float*)d_in[19]; const float* bd3 = (const float*)d_in[20];
  const float* gd2 = (const float*)d_in[21]; const float* bd2 = (const float*)d_in[22];
  const int* m1i = (const int*)d_in[23]; const int* m1o = (const int*)d_in[24];
  const int* m2i = (const int*)d_in[25]; const int* m2o = (const int*)d_in[26];
  const int* m3i = (const int*)d_in[27]; const int* m3o = (const int*)d_in[28];
  const int* m4i = (const int*)d_in[29]; const int* m4o = (const int*)d_in[30];
  const int* n1d = (const int*)d_in[31];
  const int* n2d = (const int*)d_in[32];
  const int* n3d = (const int*)d_in[33];

  const int N0 = in_sizes[0] / 4;
  const int P1 = in_sizes[23] / 27;
  const int P2 = in_sizes[25] / 27;
  const int P3 = in_sizes[27] / 27;
  const int P4 = in_sizes[29] / 27;
  const int MAXN2 = (N0 < 65536) ? N0 : 65536;  // 2 * 32^3
  const int MAXN3 = (N0 < 8192) ? N0 : 8192;    // 2 * 16^3

  char* wsb = (char*)d_ws;
  size_t off = 0;
  auto alloc = [&](size_t bytes) {
    char* p = wsb + off;
    off = (off + bytes + 255) & ~(size_t)255;
    return p;
  };
  float* stats = (float*)alloc(7 * 1024 * 4);
  int* base = (int*)alloc(32 * 4);
  int* inv = (int*)alloc((size_t)27 * N0 * 4);
  unsigned short* e1 = (unsigned short*)alloc((size_t)N0 * 32 * 2);
  unsigned short* e2 = (unsigned short*)alloc((size_t)N0 * 64 * 2);
  unsigned short* e3 = (unsigned short*)alloc((size_t)MAXN2 * 128 * 2);
  unsigned short* e4 = (unsigned short*)alloc((size_t)MAXN3 * 256 * 2);
  unsigned short* t4 = (unsigned short*)alloc((size_t)MAXN2 * 128 * 2);
  unsigned short* t3 = (unsigned short*)alloc((size_t)N0 * 64 * 2);
  unsigned short* t2 = (unsigned short*)alloc((size_t)N0 * 32 * 2);
  unsigned short* Wf2 = (unsigned short*)alloc((size_t)27 * 32 * 64 * 2);
  unsigned short* Wf3 = (unsigned short*)alloc((size_t)27 * 64 * 128 * 2);
  unsigned short* Wf4 = (unsigned short*)alloc((size_t)27 * 128 * 256 * 2);
  unsigned short* WfD4 = (unsigned short*)alloc((size_t)27 * 256 * 128 * 2);
  unsigned short* WfD3 = (unsigned short*)alloc((size_t)27 * 256 * 64 * 2);
  unsigned short* WfD2 = (unsigned short*)alloc((size_t)27 * 128 * 32 * 2);
  size_t cmax = (size_t)27 * P2 * 64;
  { size_t v;
    v = (size_t)27 * P3 * 128; if (v > cmax) cmax = v;
    v = (size_t)27 * P4 * 128; if (v > cmax) cmax = v;
    v = (size_t)27 * P3 * 64;  if (v > cmax) cmax = v;
    v = (size_t)27 * P2 * 32;  if (v > cmax) cmax = v; }
  unsigned short* contrib = (unsigned short*)alloc(cmax * 2);
  if (off > ws_size) return;  // loud fail if scratch too small

  hipMemsetAsync(stats, 0, 7 * 1024 * 4, stream);
  const dim3 blk(256);
#define ST(i) (stats + (i)*1024)
#define SB_(i) (stats + (i)*1024 + 512)

  // ---- one-time weight prep (frag-ordered bf16) ----
  prep_w_k<32, 64><<<CDIV(27 * 1 * 4 * 64, 256), blk, 0, stream>>>(W2, Wf2);
  prep_w_k<64, 128><<<CDIV(27 * 2 * 8 * 64, 256), blk, 0, stream>>>(W3, Wf3);
  prep_w_k<128, 256><<<CDIV(27 * 4 * 16 * 64, 256), blk, 0, stream>>>(W4, Wf4);
  prep_w_k<256, 128><<<CDIV(27 * 8 * 8 * 64, 256), blk, 0, stream>>>(D4w, WfD4);
  prep_w_k<256, 64><<<CDIV(27 * 8 * 4 * 64, 256), blk, 0, stream>>>(D3w, WfD3);
  prep_w_k<128, 32><<<CDIV(27 * 4 * 2 * 64, 256), blk, 0, stream>>>(D2w, WfD2);

  // ---- conv1: 4->32 scalar gather, out rows N0 ----
  fill_i32_k<<<512, blk, 0, stream>>>(inv, (long)27 * N0, -1);
  inv_build_k<<<dim3(CDIV(P1, 256), 27), blk, 0, stream>>>(m1i, m1o, P1, nullptr, N0, inv, N0);
  conv1_k<<<CDIV(N0, 8), blk, 0, stream>>>(feats, W1, inv, N0, N0, e1);
  bn_stats_bf16_k<32><<<512, blk, 0, stream>>>(e1, nullptr, N0, ST(0));
  bn_finalize_k<<<1, blk, 0, stream>>>(ST(0), g1, b1, nullptr, N0, 32, SB_(0));
  bn_apply_bf16_k<<<1024, blk, 0, stream>>>(e1, 4, SB_(0), 32, nullptr, N0);

  // ---- conv2: 32->64 compact, out rows n1 ----
  kmap_bases_k<<<1, 64, 0, stream>>>(m2o, P2, n1d, -1, base);
  fill_i32_k<<<512, blk, 0, stream>>>(inv, (long)27 * N0, -1);
  inv_scatter_k<<<dim3(CDIV(P2, 256), 27), blk, 0, stream>>>(m2o, P2, base, inv, N0);
  pgemm_k<32, 0, 64, 2><<<dim3(CDIV(P2, 128), 27), blk, 0, stream>>>(
      e1, nullptr, Wf2, m2i, P2, base, contrib);
  reduce_bf16_k<64><<<CDIV(N0, 32), blk, 0, stream>>>(contrib, inv, N0, n1d, -1, e2);
  bn_stats_bf16_k<64><<<512, blk, 0, stream>>>(e2, n1d, -1, ST(1));
  bn_finalize_k<<<1, blk, 0, stream>>>(ST(1), g2, b2, n1d, -1, 64, SB_(1));
  bn_apply_bf16_k<<<1024, blk, 0, stream>>>(e2, 8, SB_(1), 64, n1d, -1);

  // ---- conv3: 64->128 compact, out rows n2 ----
  kmap_bases_k<<<1, 64, 0, stream>>>(m3o, P3, n2d, -1, base);
  fill_i32_k<<<512, blk, 0, stream>>>(inv, (long)27 * MAXN2, -1);
  inv_scatter_k<<<dim3(CDIV(P3, 256), 27), blk, 0, stream>>>(m3o, P3, base, inv, MAXN2);
  pgemm_k<64, 0, 128, 2><<<dim3(CDIV(P3, 128), 27), blk, 0, stream>>>(
      e2, nullptr, Wf3, m3i, P3, base, contrib);
  reduce_bf16_k<128><<<CDIV(MAXN2, 16), blk, 0, stream>>>(contrib, inv, MAXN2, n2d, -1, e3);
  bn_stats_bf16_k<128><<<512, blk, 0, stream>>>(e3, n2d, -1, ST(2));
  bn_finalize_k<<<1, blk, 0, stream>>>(ST(2), g3, b3, n2d, -1, 128, SB_(2));
  bn_apply_bf16_k<<<1024, blk, 0, stream>>>(e3, 16, SB_(2), 128, n2d, -1);

  // ---- conv4: 128->256 dense MFMA (84% fill), out rows n3, col-split x4 ----
  fill_i32_k<<<512, blk, 0, stream>>>(inv, (long)27 * MAXN3, -1);
  inv_build_k<<<dim3(CDIV(P4, 256), 27), blk, 0, stream>>>(m4i, m4o, P4, n3d, -1, inv, MAXN3);
  mconv_k<128, 0, 256, 4, 8><<<dim3(CDIV(MAXN3, 128), 4), 512, 0, stream>>>(
      e3, nullptr, Wf4, inv, MAXN3, n3d, -1, e4, ST(3));
  bn_finalize_k<<<1, blk, 0, stream>>>(ST(3), g4, b4, n3d, -1, 256, SB_(3));
  bn_apply_bf16_k<<<512, blk, 0, stream>>>(e4, 32, SB_(3), 256, n3d, -1);

  // ---- D4: tconv 256->128 compact (maps swapped), out rows n2 ----
  kmap_bases_k<<<1, 64, 0, stream>>>(m4i, P4, n2d, -1, base);
  fill_i32_k<<<512, blk, 0, stream>>>(inv, (long)27 * MAXN2, -1);
  inv_scatter_k<<<dim3(CDIV(P4, 256), 27), blk, 0, stream>>>(m4i, P4, base, inv, MAXN2);
  pgemm_k<256, 0, 128, 2><<<dim3(CDIV(P4, 128), 27), blk, 0, stream>>>(
      e4, nullptr, WfD4, m4o, P4, base, contrib);
  reduce_bf16_k<128><<<CDIV(MAXN2, 16), blk, 0, stream>>>(contrib, inv, MAXN2, n2d, -1, t4);
  bn_stats_bf16_k<128><<<512, blk, 0, stream>>>(t4, n2d, -1, ST(4));
  bn_finalize_k<<<1, blk, 0, stream>>>(ST(4), gd4, bd4, n2d, -1, 128, SB_(4));
  bn_apply_bf16_k<<<1024, blk, 0, stream>>>(t4, 16, SB_(4), 128, n2d, -1);

  // ---- D3: tconv concat(t4,e3)=256 -> 64 compact, out rows n1 ----
  kmap_bases_k<<<1, 64, 0, stream>>>(m3i, P3, n1d, -1, base);
  fill_i32_k<<<512, blk, 0, stream>>>(inv, (long)27 * N0, -1);
  inv_scatter_k<<<dim3(CDIV(P3, 256), 27), blk, 0, stream>>>(m3i, P3, base, inv, N0);
  pgemm_k<128, 128, 64, 2><<<dim3(CDIV(P3, 128), 27), blk, 0, stream>>>(
      t4, e3, WfD3, m3o, P3, base, contrib);
  reduce_bf16_k<64><<<CDIV(N0, 32), blk, 0, stream>>>(contrib, inv, N0, n1d, -1, t3);
  bn_stats_bf16_k<64><<<512, blk, 0, stream>>>(t3, n1d, -1, ST(5));
  bn_finalize_k<<<1, blk, 0, stream>>>(ST(5), gd3, bd3, n1d, -1, 64, SB_(5));
  bn_apply_bf16_k<<<1024, blk, 0, stream>>>(t3, 8, SB_(5), 64, n1d, -1);

  // ---- D2: tconv concat(t3,e2)=128 -> 32 compact, out rows N0 ----
  kmap_bases_k<<<1, 64, 0, stream>>>(m2i, P2, nullptr, N0, base);
  fill_i32_k<<<512, blk, 0, stream>>>(inv, (long)27 * N0, -1);
  inv_scatter_k<<<dim3(CDIV(P2, 256), 27), blk, 0, stream>>>(m2i, P2, base, inv, N0);
  pgemm_k<64, 64, 32, 2><<<dim3(CDIV(P2, 128), 27), blk, 0, stream>>>(
      t3, e2, WfD2, m2o, P2, base, contrib);
  reduce_bf16_k<32><<<CDIV(N0, 64), blk, 0, stream>>>(contrib, inv, N0, nullptr, N0, t2);
  bn_stats_bf16_k<32><<<512, blk, 0, stream>>>(t2, nullptr, N0, ST(6));
  bn_finalize_k<<<1, blk, 0, stream>>>(ST(6), gd2, bd2, nullptr, N0, 32, SB_(6));
  bn_apply_bf16_k<<<1024, blk, 0, stream>>>(t2, 4, SB_(6), 32, nullptr, N0);

  // ---- final 1x1: out = concat(t2, e1) @ Wf ----
  final_gemm_k<<<CDIV(N0, 256), blk, 0, stream>>>(t2, e1, Wf, (float*)d_out, N0);

#undef ST
#undef SB_
}